// Round 1
// baseline (650.809 us; speedup 1.0000x reference)
//
#include <hip/hip_runtime.h>
#include <math.h>

// Problem constants (from reference)
#define NBLK   4      // NB: blocks
#define NH     8      // H: heads
#define BATCH  2      // B
#define SEQ    1024   // S
#define DIM    512    // D
#define HIDDEN 512    // HID
#define MODF   1.55f  // MOD = 0.5*1.1+0.5*0.7+0.5*1.3
#define INV_SQRT_HID 0.04419417382415922f  // 1/sqrt(512)

constexpr int TM = 64, TN = 64, TK = 16;
constexpr int PAD = 4;  // pad to 68 floats/row: keeps float4 LDS reads 16B-aligned

// ---------------------------------------------------------------------------
// Generic fp32 tile-GEMM core. C-tile accumulation over K.
// BT=false: C += A[M,K] @ B[K,N]      (both row-major)
// BT=true : C += A[M,K] @ B[N,K]^T   (dot over last dim of both)
// block = 256 threads; each computes a 4x4 microtile of the 64x64 C tile.
// ---------------------------------------------------------------------------
template<bool BT>
__device__ __forceinline__ void gemm_tile(
    const float* __restrict__ A, int lda,
    const float* __restrict__ B, int ldb,
    int K, int m0, int n0, float (&acc)[4][4])
{
    __shared__ float As[TK][TM + PAD];
    __shared__ float Bs[TK][TN + PAD];
    const int tid = threadIdx.x;
    const int tx = tid & 15, ty = tid >> 4;

    for (int k0 = 0; k0 < K; k0 += TK) {
        // ---- stage A tile: As[k][m] = A[m0+m][k0+k] ----
        {
            const int m  = tid >> 2;
            const int kv = (tid & 3) << 2;
            const float4 a = *(const float4*)(A + (size_t)(m0 + m) * lda + (k0 + kv));
            As[kv + 0][m] = a.x; As[kv + 1][m] = a.y;
            As[kv + 2][m] = a.z; As[kv + 3][m] = a.w;
        }
        // ---- stage B tile: Bs[k][n] ----
        if (BT) {
            const int t  = tid >> 2;
            const int kv = (tid & 3) << 2;
            const float4 b = *(const float4*)(B + (size_t)(n0 + t) * ldb + (k0 + kv));
            Bs[kv + 0][t] = b.x; Bs[kv + 1][t] = b.y;
            Bs[kv + 2][t] = b.z; Bs[kv + 3][t] = b.w;
        } else {
            const int k  = tid >> 4;
            const int nv = (tid & 15) << 2;
            const float4 b = *(const float4*)(B + (size_t)(k0 + k) * ldb + (n0 + nv));
            *(float4*)&Bs[k][nv] = b;
        }
        __syncthreads();

#pragma unroll
        for (int kk = 0; kk < TK; ++kk) {
            const float4 a = *(const float4*)&As[kk][ty << 2];
            const float4 b = *(const float4*)&Bs[kk][tx << 2];
            acc[0][0] += a.x * b.x; acc[0][1] += a.x * b.y; acc[0][2] += a.x * b.z; acc[0][3] += a.x * b.w;
            acc[1][0] += a.y * b.x; acc[1][1] += a.y * b.y; acc[1][2] += a.y * b.z; acc[1][3] += a.y * b.w;
            acc[2][0] += a.z * b.x; acc[2][1] += a.z * b.y; acc[2][2] += a.z * b.z; acc[2][3] += a.z * b.w;
            acc[3][0] += a.w * b.x; acc[3][1] += a.w * b.y; acc[3][2] += a.w * b.z; acc[3][3] += a.w * b.w;
        }
        __syncthreads();
    }
}

// ---------------------------------------------------------------------------
// Kernel 1: QKV projections.  z = which*NBLK + n  (which: 0=Q,1=K,2=V)
// Q/K/V[n][m=b*S+s][h] = x[m] . W[n][:,h] + bias[n][h]
// ---------------------------------------------------------------------------
__global__ __launch_bounds__(256) void proj_kernel(
    const float* __restrict__ x,
    const float* __restrict__ Wq, const float* __restrict__ bq,
    const float* __restrict__ Wk, const float* __restrict__ bk,
    const float* __restrict__ Wv, const float* __restrict__ bv,
    float* __restrict__ Qb, float* __restrict__ Kb, float* __restrict__ Vb)
{
    const int z = blockIdx.z;
    const int n = z & 3, which = z >> 2;
    const float* W; const float* bias; float* Cbuf;
    if (which == 0)      { W = Wq; bias = bq; Cbuf = Qb; }
    else if (which == 1) { W = Wk; bias = bk; Cbuf = Kb; }
    else                 { W = Wv; bias = bv; Cbuf = Vb; }
    W    += (size_t)n * DIM * HIDDEN;
    bias += (size_t)n * HIDDEN;
    float* C = Cbuf + (size_t)n * BATCH * SEQ * HIDDEN;

    const int m0 = blockIdx.y * TM, n0 = blockIdx.x * TN;
    float acc[4][4] = {};
    gemm_tile<false>(x, DIM, W, HIDDEN, DIM, m0, n0, acc);

    const int tx = threadIdx.x & 15, ty = threadIdx.x >> 4;
    const int c = n0 + (tx << 2);
    const float4 bv4 = *(const float4*)(bias + c);
#pragma unroll
    for (int i = 0; i < 4; ++i) {
        const int r = m0 + (ty << 2) + i;
        float4 o = make_float4(acc[i][0] + bv4.x, acc[i][1] + bv4.y,
                               acc[i][2] + bv4.z, acc[i][3] + bv4.w);
        *(float4*)(C + (size_t)r * HIDDEN + c) = o;
    }
}

// ---------------------------------------------------------------------------
// Kernel 2: scores[z][s][t] = (Q[z][s] . K[z][t]) / sqrt(HID),  z = n*BATCH+b
// ---------------------------------------------------------------------------
__global__ __launch_bounds__(256) void scores_kernel(
    const float* __restrict__ Qb, const float* __restrict__ Kb,
    float* __restrict__ P)
{
    const int z = blockIdx.z;
    const float* Aq = Qb + (size_t)z * SEQ * HIDDEN;
    const float* Bk = Kb + (size_t)z * SEQ * HIDDEN;
    float* C = P + (size_t)z * SEQ * SEQ;

    const int m0 = blockIdx.y * TM, n0 = blockIdx.x * TN;
    float acc[4][4] = {};
    gemm_tile<true>(Aq, HIDDEN, Bk, HIDDEN, HIDDEN, m0, n0, acc);

    const int tx = threadIdx.x & 15, ty = threadIdx.x >> 4;
    const int c = n0 + (tx << 2);
#pragma unroll
    for (int i = 0; i < 4; ++i) {
        const int r = m0 + (ty << 2) + i;
        float4 o = make_float4(acc[i][0] * INV_SQRT_HID, acc[i][1] * INV_SQRT_HID,
                               acc[i][2] * INV_SQRT_HID, acc[i][3] * INV_SQRT_HID);
        *(float4*)(C + (size_t)r * SEQ + c) = o;
    }
}

// ---------------------------------------------------------------------------
// Kernel 3: in-place per-row combine of 8 gated softmaxes.
// row of P (length S). s_h>0 so per-head max = s_h * rowmax.
// P[t] <- sum_h gate_h * exp(s_h*(x_t - M)) / Z_h
// one 256-thread block per row; each thread owns 4 contiguous elements.
// ---------------------------------------------------------------------------
__global__ __launch_bounds__(256) void softmax_combine_kernel(
    float* __restrict__ P,
    const float* __restrict__ strength, const float* __restrict__ gate)
{
    const int row = blockIdx.x;              // [0, NBLK*BATCH*SEQ)
    const int n = row >> 11;                 // row / (BATCH*SEQ)
    float* prow = P + (size_t)row * SEQ;
    const int tid = threadIdx.x;
    const int wid = tid >> 6, lane = tid & 63;

    float4 v = ((const float4*)prow)[tid];

    // ---- block row-max ----
    float m = fmaxf(fmaxf(v.x, v.y), fmaxf(v.z, v.w));
#pragma unroll
    for (int off = 32; off > 0; off >>= 1) m = fmaxf(m, __shfl_down(m, off));
    __shared__ float redm[4];
    if (lane == 0) redm[wid] = m;
    __syncthreads();
    const float M = fmaxf(fmaxf(redm[0], redm[1]), fmaxf(redm[2], redm[3]));

    // ---- per-head params ----
    float sh[NH], gh[NH];
#pragma unroll
    for (int h = 0; h < NH; ++h) {
        sh[h] = fminf(fmaxf(strength[n * NH * NH + h * NH + h], 0.01f), 1.0f);
        gh[h] = gate[n * NH + h];
    }

    // ---- exp + per-head partial sums ----
    const float e[4] = { v.x - M, v.y - M, v.z - M, v.w - M };
    float E[4][NH];
    float zsum[NH];
#pragma unroll
    for (int h = 0; h < NH; ++h) zsum[h] = 0.f;
#pragma unroll
    for (int i = 0; i < 4; ++i)
#pragma unroll
        for (int h = 0; h < NH; ++h) {
            const float t = __expf(sh[h] * e[i]);
            E[i][h] = t; zsum[h] += t;
        }

    // ---- block reduce the 8 sums ----
#pragma unroll
    for (int h = 0; h < NH; ++h)
#pragma unroll
        for (int off = 32; off > 0; off >>= 1) zsum[h] += __shfl_down(zsum[h], off);
    __shared__ float redz[4][NH];
    if (lane == 0)
#pragma unroll
        for (int h = 0; h < NH; ++h) redz[wid][h] = zsum[h];
    __syncthreads();

    float w[NH];
#pragma unroll
    for (int h = 0; h < NH; ++h) {
        const float Z = redz[0][h] + redz[1][h] + redz[2][h] + redz[3][h];
        w[h] = gh[h] / Z;
    }

    // ---- combined probabilities, in place ----
    float c[4];
#pragma unroll
    for (int i = 0; i < 4; ++i) {
        float s = 0.f;
#pragma unroll
        for (int h = 0; h < NH; ++h) s += w[h] * E[i][h];
        c[i] = s;
    }
    ((float4*)prow)[tid] = make_float4(c[0], c[1], c[2], c[3]);
}

// ---------------------------------------------------------------------------
// Kernel 4: head_sum[z][s][d] = P[z] @ V[z]
// ---------------------------------------------------------------------------
__global__ __launch_bounds__(256) void pv_kernel(
    const float* __restrict__ P, const float* __restrict__ Vb,
    float* __restrict__ HS)
{
    const int z = blockIdx.z;
    const float* Ap = P + (size_t)z * SEQ * SEQ;
    const float* Bv = Vb + (size_t)z * SEQ * HIDDEN;
    float* C = HS + (size_t)z * SEQ * HIDDEN;

    const int m0 = blockIdx.y * TM, n0 = blockIdx.x * TN;
    float acc[4][4] = {};
    gemm_tile<false>(Ap, SEQ, Bv, HIDDEN, SEQ, m0, n0, acc);

    const int tx = threadIdx.x & 15, ty = threadIdx.x >> 4;
    const int c = n0 + (tx << 2);
#pragma unroll
    for (int i = 0; i < 4; ++i) {
        const int r = m0 + (ty << 2) + i;
        *(float4*)(C + (size_t)r * HIDDEN + c) =
            make_float4(acc[i][0], acc[i][1], acc[i][2], acc[i][3]);
    }
}

// ---------------------------------------------------------------------------
// Kernel 5: out[m][o] = MOD * ( sum_n (HS[n][m] . Wo[n][:,o]) + sum_n bo[n][o] )
// ---------------------------------------------------------------------------
__global__ __launch_bounds__(256) void out_kernel(
    const float* __restrict__ HS, const float* __restrict__ Wo,
    const float* __restrict__ bo, float* __restrict__ out)
{
    const int m0 = blockIdx.y * TM, n0 = blockIdx.x * TN;
    float acc[4][4] = {};
#pragma unroll
    for (int n = 0; n < NBLK; ++n)
        gemm_tile<false>(HS + (size_t)n * BATCH * SEQ * HIDDEN, HIDDEN,
                         Wo + (size_t)n * HIDDEN * DIM, DIM,
                         HIDDEN, m0, n0, acc);

    const int tx = threadIdx.x & 15, ty = threadIdx.x >> 4;
    const int c = n0 + (tx << 2);
    float bsum[4];
#pragma unroll
    for (int j = 0; j < 4; ++j) {
        float s = 0.f;
#pragma unroll
        for (int n = 0; n < NBLK; ++n) s += bo[n * DIM + c + j];
        bsum[j] = s;
    }
#pragma unroll
    for (int i = 0; i < 4; ++i) {
        const int r = m0 + (ty << 2) + i;
        *(float4*)(out + (size_t)r * DIM + c) =
            make_float4((acc[i][0] + bsum[0]) * MODF, (acc[i][1] + bsum[1]) * MODF,
                        (acc[i][2] + bsum[2]) * MODF, (acc[i][3] + bsum[3]) * MODF);
    }
}

// ---------------------------------------------------------------------------
extern "C" void kernel_launch(void* const* d_in, const int* in_sizes, int n_in,
                              void* d_out, int out_size, void* d_ws, size_t ws_size,
                              hipStream_t stream) {
    const float* x        = (const float*)d_in[0];
    const float* Wq       = (const float*)d_in[1];
    const float* bq       = (const float*)d_in[2];
    const float* Wk       = (const float*)d_in[3];
    const float* bk       = (const float*)d_in[4];
    const float* Wv       = (const float*)d_in[5];
    const float* bv       = (const float*)d_in[6];
    const float* Wo       = (const float*)d_in[7];
    const float* bo       = (const float*)d_in[8];
    const float* strength = (const float*)d_in[9];
    const float* gate     = (const float*)d_in[10];
    float* out = (float*)d_out;

    // workspace layout (floats):
    //   Q : NBLK*BATCH*SEQ*HIDDEN = 4,194,304
    //   K : 4,194,304
    //   V : 4,194,304
    //   P : NBLK*BATCH*SEQ*SEQ    = 8,388,608
    //   HS aliases Q (Q is dead after scores_kernel)
    // total = 20,971,520 floats = 80 MiB
    float* ws = (float*)d_ws;
    const size_t QSZ = (size_t)NBLK * BATCH * SEQ * HIDDEN;
    float* Qb = ws;
    float* Kb = Qb + QSZ;
    float* Vb = Kb + QSZ;
    float* Pb = Vb + QSZ;
    float* HS = Qb;  // alias: safe, Q consumed before pv_kernel writes

    // 1) QKV projections: M=2048, N=512 tiles of 64 -> grid (8, 32, 12)
    proj_kernel<<<dim3(HIDDEN / TN, (BATCH * SEQ) / TM, 3 * NBLK), 256, 0, stream>>>(
        x, Wq, bq, Wk, bk, Wv, bv, Qb, Kb, Vb);

    // 2) scores: M=N=1024 -> grid (16, 16, 8)
    scores_kernel<<<dim3(SEQ / TN, SEQ / TM, NBLK * BATCH), 256, 0, stream>>>(Qb, Kb, Pb);

    // 3) softmax-combine over heads, in place: one block per row
    softmax_combine_kernel<<<dim3(NBLK * BATCH * SEQ), 256, 0, stream>>>(Pb, strength, gate);

    // 4) head_sum = P @ V: M=1024, N=512 -> grid (8, 16, 8)
    pv_kernel<<<dim3(HIDDEN / TN, SEQ / TM, NBLK * BATCH), 256, 0, stream>>>(Pb, Vb, HS);

    // 5) output projection + block-sum + bias + MOD: grid (8, 32)
    out_kernel<<<dim3(DIM / TN, (BATCH * SEQ) / TM, 1), 256, 0, stream>>>(HS, Wo, bo, out);
}

// Round 4
// 563.525 us; speedup vs baseline: 1.1549x; 1.1549x over previous
//
#include <hip/hip_runtime.h>
#include <math.h>

// Problem constants (from reference)
#define NBLK   4      // NB: blocks
#define NH     8      // H: heads
#define BATCH  2      // B
#define SEQ    1024   // S
#define DIM    512    // D
#define HIDDEN 512    // HID
#define MODF   1.55f  // MOD
#define INV_SQRT_HID 0.04419417382415922f  // 1/sqrt(512)

typedef __bf16 bf16;
typedef __bf16 bf16x4 __attribute__((ext_vector_type(4)));
typedef __bf16 bf16x8 __attribute__((ext_vector_type(8)));
typedef float  floatx4 __attribute__((ext_vector_type(4)));

// ---------------- fp32 vector-GEMM core (R1, PROVEN) ----------------
constexpr int TM = 64, TN = 64, TK = 16;
constexpr int PAD = 4;

template<bool BT>
__device__ __forceinline__ void gemm_tile(
    const float* __restrict__ A, int lda,
    const float* __restrict__ B, int ldb,
    int K, int m0, int n0, float (&acc)[4][4])
{
    __shared__ float As[TK][TM + PAD];
    __shared__ float Bs[TK][TN + PAD];
    const int tid = threadIdx.x;
    const int tx = tid & 15, ty = tid >> 4;

    for (int k0 = 0; k0 < K; k0 += TK) {
        {
            const int m  = tid >> 2;
            const int kv = (tid & 3) << 2;
            const float4 a = *(const float4*)(A + (size_t)(m0 + m) * lda + (k0 + kv));
            As[kv + 0][m] = a.x; As[kv + 1][m] = a.y;
            As[kv + 2][m] = a.z; As[kv + 3][m] = a.w;
        }
        if (BT) {
            const int t  = tid >> 2;
            const int kv = (tid & 3) << 2;
            const float4 b = *(const float4*)(B + (size_t)(n0 + t) * ldb + (k0 + kv));
            Bs[kv + 0][t] = b.x; Bs[kv + 1][t] = b.y;
            Bs[kv + 2][t] = b.z; Bs[kv + 3][t] = b.w;
        } else {
            const int k  = tid >> 4;
            const int nv = (tid & 15) << 2;
            const float4 b = *(const float4*)(B + (size_t)(k0 + k) * ldb + (n0 + nv));
            *(float4*)&Bs[k][nv] = b;
        }
        __syncthreads();

#pragma unroll
        for (int kk = 0; kk < TK; ++kk) {
            const float4 a = *(const float4*)&As[kk][ty << 2];
            const float4 b = *(const float4*)&Bs[kk][tx << 2];
            acc[0][0] += a.x * b.x; acc[0][1] += a.x * b.y; acc[0][2] += a.x * b.z; acc[0][3] += a.x * b.w;
            acc[1][0] += a.y * b.x; acc[1][1] += a.y * b.y; acc[1][2] += a.y * b.z; acc[1][3] += a.y * b.w;
            acc[2][0] += a.z * b.x; acc[2][1] += a.z * b.y; acc[2][2] += a.z * b.z; acc[2][3] += a.z * b.w;
            acc[3][0] += a.w * b.x; acc[3][1] += a.w * b.y; acc[3][2] += a.w * b.z; acc[3][3] += a.w * b.w;
        }
        __syncthreads();
    }
}

// ---------------- bf16 MFMA NT core (under test, isolated to scores) -------
constexpr int BM = 128, BN = 128, BK = 32;
constexpr int BKP = 40;   // padded LDS K-stride (80 B, 16B-aligned)

__device__ __forceinline__ void mfma_nt(
    const bf16* __restrict__ A, int lda,
    const bf16* __restrict__ B, int ldb,
    int K, int m0, int n0, floatx4 (&acc)[4][4])
{
    __shared__ __align__(16) bf16 As[BM * BKP];
    __shared__ __align__(16) bf16 Bs[BN * BKP];

    const int tid = threadIdx.x;
    const int l   = tid & 63;
    const int w   = tid >> 6;
    const int wr  = (w >> 1) * 64;
    const int wc  = (w & 1) * 64;

    const int srow = tid >> 2;         // 0..63
    const int scol = (tid & 3) * 8;    // 0,8,16,24

    const int fr = l & 15;
    const int fk = (l >> 4) * 8;

    const bf16* Ab = A + (size_t)m0 * lda;
    const bf16* Bb = B + (size_t)n0 * ldb;

    for (int k0 = 0; k0 < K; k0 += BK) {
        const bf16x8 ra0 = *(const bf16x8*)(Ab + (size_t)srow        * lda + k0 + scol);
        const bf16x8 ra1 = *(const bf16x8*)(Ab + (size_t)(srow + 64) * lda + k0 + scol);
        const bf16x8 rb0 = *(const bf16x8*)(Bb + (size_t)srow        * ldb + k0 + scol);
        const bf16x8 rb1 = *(const bf16x8*)(Bb + (size_t)(srow + 64) * ldb + k0 + scol);

        __syncthreads();
        *(bf16x8*)&As[srow        * BKP + scol] = ra0;
        *(bf16x8*)&As[(srow + 64) * BKP + scol] = ra1;
        *(bf16x8*)&Bs[srow        * BKP + scol] = rb0;
        *(bf16x8*)&Bs[(srow + 64) * BKP + scol] = rb1;
        __syncthreads();

        bf16x8 af[4], bg[4];
#pragma unroll
        for (int i = 0; i < 4; ++i)
            af[i] = *(const bf16x8*)&As[(wr + i * 16 + fr) * BKP + fk];
#pragma unroll
        for (int j = 0; j < 4; ++j)
            bg[j] = *(const bf16x8*)&Bs[(wc + j * 16 + fr) * BKP + fk];
#pragma unroll
        for (int i = 0; i < 4; ++i)
#pragma unroll
            for (int j = 0; j < 4; ++j)
                acc[i][j] = __builtin_amdgcn_mfma_f32_16x16x32_bf16(
                    af[i], bg[j], acc[i][j], 0, 0, 0);
    }
}

// ---------------------------------------------------------------------------
// Kernel 1 (R1-proven + bf16 store for Q/K): z = which*NBLK + n
// which 0=Q, 1=K  -> bf16 out (only consumer is MFMA scores)
// which 2=V      -> fp32 out (R1 path)
// ---------------------------------------------------------------------------
__global__ __launch_bounds__(256) void proj_kernel(
    const float* __restrict__ x,
    const float* __restrict__ Wq, const float* __restrict__ bq,
    const float* __restrict__ Wk, const float* __restrict__ bk,
    const float* __restrict__ Wv, const float* __restrict__ bv,
    bf16* __restrict__ Qh, bf16* __restrict__ Kh, float* __restrict__ Vb)
{
    const int z = blockIdx.z;
    const int n = z & 3, which = z >> 2;
    const float* W; const float* bias;
    if (which == 0)      { W = Wq; bias = bq; }
    else if (which == 1) { W = Wk; bias = bk; }
    else                 { W = Wv; bias = bv; }
    W    += (size_t)n * DIM * HIDDEN;
    bias += (size_t)n * HIDDEN;

    const int m0 = blockIdx.y * TM, n0 = blockIdx.x * TN;
    float acc[4][4] = {};
    gemm_tile<false>(x, DIM, W, HIDDEN, DIM, m0, n0, acc);

    const int tx = threadIdx.x & 15, ty = threadIdx.x >> 4;
    const int c = n0 + (tx << 2);
    const float4 bv4 = *(const float4*)(bias + c);

    if (which == 2) {
        float* C = Vb + (size_t)n * BATCH * SEQ * HIDDEN;
#pragma unroll
        for (int i = 0; i < 4; ++i) {
            const int r = m0 + (ty << 2) + i;
            *(float4*)(C + (size_t)r * HIDDEN + c) =
                make_float4(acc[i][0] + bv4.x, acc[i][1] + bv4.y,
                            acc[i][2] + bv4.z, acc[i][3] + bv4.w);
        }
    } else {
        bf16* C = (which ? Kh : Qh) + (size_t)n * BATCH * SEQ * HIDDEN;
#pragma unroll
        for (int i = 0; i < 4; ++i) {
            const int r = m0 + (ty << 2) + i;
            bf16x4 o = { (bf16)(acc[i][0] + bv4.x), (bf16)(acc[i][1] + bv4.y),
                         (bf16)(acc[i][2] + bv4.z), (bf16)(acc[i][3] + bv4.w) };
            *(bf16x4*)&C[(size_t)r * HIDDEN + c] = o;
        }
    }
}

// ---------------------------------------------------------------------------
// Kernel 2 (MFMA, under test): P[z][s][t] = (Q[z][s].K[z][t]) / sqrt(HID)
// z = n*BATCH + b; Q/K layout [n][m=b*S+s][h] -> base + z*SEQ*HIDDEN.
// ---------------------------------------------------------------------------
__global__ __launch_bounds__(256) void scores_mfma_kernel(
    const bf16* __restrict__ Qh, const bf16* __restrict__ Kh,
    float* __restrict__ P)
{
    const int z = blockIdx.z;
    const bf16* A = Qh + (size_t)z * SEQ * HIDDEN;
    const bf16* B = Kh + (size_t)z * SEQ * HIDDEN;
    float* C = P + (size_t)z * SEQ * SEQ;

    const int m0 = blockIdx.y * BM, n0 = blockIdx.x * BN;
    floatx4 acc[4][4] = {};
    mfma_nt(A, HIDDEN, B, HIDDEN, HIDDEN, m0, n0, acc);

    // C/D layout (m89/m91): col = lane&15 (+16j), row = (lane>>4)*4 + r (+16i)
    const int l = threadIdx.x & 63, w = threadIdx.x >> 6;
    const int rb = m0 + (w >> 1) * 64 + (l >> 4) * 4;
    const int cb = n0 + (w & 1) * 64 + (l & 15);
#pragma unroll
    for (int i = 0; i < 4; ++i)
#pragma unroll
        for (int j = 0; j < 4; ++j)
#pragma unroll
            for (int r = 0; r < 4; ++r)
                C[(size_t)(rb + i * 16 + r) * SEQ + cb + j * 16] =
                    acc[i][j][r] * INV_SQRT_HID;
}

// ---------------------------------------------------------------------------
// Kernel 3 (R1 verbatim): in-place fp32 softmax-combine over 8 gated heads.
// ---------------------------------------------------------------------------
__global__ __launch_bounds__(256) void softmax_combine_kernel(
    float* __restrict__ P,
    const float* __restrict__ strength, const float* __restrict__ gate)
{
    const int row = blockIdx.x;
    const int n = row >> 11;
    float* prow = P + (size_t)row * SEQ;
    const int tid = threadIdx.x;
    const int wid = tid >> 6, lane = tid & 63;

    float4 v = ((const float4*)prow)[tid];

    float m = fmaxf(fmaxf(v.x, v.y), fmaxf(v.z, v.w));
#pragma unroll
    for (int off = 32; off > 0; off >>= 1) m = fmaxf(m, __shfl_down(m, off));
    __shared__ float redm[4];
    if (lane == 0) redm[wid] = m;
    __syncthreads();
    const float M = fmaxf(fmaxf(redm[0], redm[1]), fmaxf(redm[2], redm[3]));

    float sh[NH], gh[NH];
#pragma unroll
    for (int h = 0; h < NH; ++h) {
        sh[h] = fminf(fmaxf(strength[n * NH * NH + h * NH + h], 0.01f), 1.0f);
        gh[h] = gate[n * NH + h];
    }

    const float e[4] = { v.x - M, v.y - M, v.z - M, v.w - M };
    float E[4][NH];
    float zsum[NH];
#pragma unroll
    for (int h = 0; h < NH; ++h) zsum[h] = 0.f;
#pragma unroll
    for (int i = 0; i < 4; ++i)
#pragma unroll
        for (int h = 0; h < NH; ++h) {
            const float t = __expf(sh[h] * e[i]);
            E[i][h] = t; zsum[h] += t;
        }

#pragma unroll
    for (int h = 0; h < NH; ++h)
#pragma unroll
        for (int off = 32; off > 0; off >>= 1) zsum[h] += __shfl_down(zsum[h], off);
    __shared__ float redz[4][NH];
    if (lane == 0)
#pragma unroll
        for (int h = 0; h < NH; ++h) redz[wid][h] = zsum[h];
    __syncthreads();

    float wgt[NH];
#pragma unroll
    for (int h = 0; h < NH; ++h) {
        const float Z = redz[0][h] + redz[1][h] + redz[2][h] + redz[3][h];
        wgt[h] = gh[h] / Z;
    }

    float c[4];
#pragma unroll
    for (int i = 0; i < 4; ++i) {
        float s = 0.f;
#pragma unroll
        for (int h = 0; h < NH; ++h) s += wgt[h] * E[i][h];
        c[i] = s;
    }
    ((float4*)prow)[tid] = make_float4(c[0], c[1], c[2], c[3]);
}

// ---------------------------------------------------------------------------
// Kernel 4 (R1 verbatim): HS[z][s][d] = P[z] @ V[z]
// ---------------------------------------------------------------------------
__global__ __launch_bounds__(256) void pv_kernel(
    const float* __restrict__ P, const float* __restrict__ Vb,
    float* __restrict__ HS)
{
    const int z = blockIdx.z;
    const float* Ap = P + (size_t)z * SEQ * SEQ;
    const float* Bv = Vb + (size_t)z * SEQ * HIDDEN;
    float* C = HS + (size_t)z * SEQ * HIDDEN;

    const int m0 = blockIdx.y * TM, n0 = blockIdx.x * TN;
    float acc[4][4] = {};
    gemm_tile<false>(Ap, SEQ, Bv, HIDDEN, SEQ, m0, n0, acc);

    const int tx = threadIdx.x & 15, ty = threadIdx.x >> 4;
    const int c = n0 + (tx << 2);
#pragma unroll
    for (int i = 0; i < 4; ++i) {
        const int r = m0 + (ty << 2) + i;
        *(float4*)(C + (size_t)r * HIDDEN + c) =
            make_float4(acc[i][0], acc[i][1], acc[i][2], acc[i][3]);
    }
}

// ---------------------------------------------------------------------------
// Kernel 5 (R1 verbatim): out[m][o] = MOD*(sum_n HS[n][m].Wo[n][:,o] + sum_n bo)
// ---------------------------------------------------------------------------
__global__ __launch_bounds__(256) void out_kernel(
    const float* __restrict__ HS, const float* __restrict__ Wo,
    const float* __restrict__ bo, float* __restrict__ out)
{
    const int m0 = blockIdx.y * TM, n0 = blockIdx.x * TN;
    float acc[4][4] = {};
#pragma unroll
    for (int n = 0; n < NBLK; ++n)
        gemm_tile<false>(HS + (size_t)n * BATCH * SEQ * HIDDEN, HIDDEN,
                         Wo + (size_t)n * HIDDEN * DIM, DIM,
                         HIDDEN, m0, n0, acc);

    const int tx = threadIdx.x & 15, ty = threadIdx.x >> 4;
    const int c = n0 + (tx << 2);
    float bsum[4];
#pragma unroll
    for (int j = 0; j < 4; ++j) {
        float s = 0.f;
#pragma unroll
        for (int n = 0; n < NBLK; ++n) s += bo[n * DIM + c + j];
        bsum[j] = s;
    }
#pragma unroll
    for (int i = 0; i < 4; ++i) {
        const int r = m0 + (ty << 2) + i;
        *(float4*)(out + (size_t)r * DIM + c) =
            make_float4((acc[i][0] + bsum[0]) * MODF, (acc[i][1] + bsum[1]) * MODF,
                        (acc[i][2] + bsum[2]) * MODF, (acc[i][3] + bsum[3]) * MODF);
    }
}

// ---------------------------------------------------------------------------
extern "C" void kernel_launch(void* const* d_in, const int* in_sizes, int n_in,
                              void* d_out, int out_size, void* d_ws, size_t ws_size,
                              hipStream_t stream) {
    const float* x        = (const float*)d_in[0];
    const float* Wq       = (const float*)d_in[1];
    const float* bq       = (const float*)d_in[2];
    const float* Wk       = (const float*)d_in[3];
    const float* bk       = (const float*)d_in[4];
    const float* Wv       = (const float*)d_in[5];
    const float* bv       = (const float*)d_in[6];
    const float* Wo       = (const float*)d_in[7];
    const float* bo       = (const float*)d_in[8];
    const float* strength = (const float*)d_in[9];
    const float* gate     = (const float*)d_in[10];
    float* out = (float*)d_out;

    // workspace (bytes), total 80 MiB (== R1's proven footprint):
    //   Qh bf16  0 .. 8 MiB
    //   Kh bf16  8 .. 16 MiB
    //   Vb fp32 16 .. 32 MiB
    //   Pf fp32 32 .. 64 MiB
    //   HS fp32 64 .. 80 MiB
    char* ws = (char*)d_ws;
    bf16*  Qh = (bf16*)(ws);
    bf16*  Kh = (bf16*)(ws + 8388608);
    float* Vb = (float*)(ws + 16777216);
    float* Pf = (float*)(ws + 33554432);
    float* HS = (float*)(ws + 67108864);

    // 1) QKV projections (fp32 core; Q/K stored bf16, V fp32)
    proj_kernel<<<dim3(HIDDEN / TN, (BATCH * SEQ) / TM, 3 * NBLK), 256, 0, stream>>>(
        x, Wq, bq, Wk, bk, Wv, bv, Qh, Kh, Vb);

    // 2) scores via MFMA (the isolated stage under test): grid (8,8,8)
    scores_mfma_kernel<<<dim3(SEQ / BN, SEQ / BM, NBLK * BATCH), 256, 0, stream>>>(
        Qh, Kh, Pf);

    // 3) softmax-combine in place (fp32)
    softmax_combine_kernel<<<dim3(NBLK * BATCH * SEQ), 256, 0, stream>>>(
        Pf, strength, gate);

    // 4) head_sum = P @ V (fp32)
    pv_kernel<<<dim3(HIDDEN / TN, SEQ / TM, NBLK * BATCH), 256, 0, stream>>>(Pf, Vb, HS);

    // 5) output projection (fp32)
    out_kernel<<<dim3(DIM / TN, (BATCH * SEQ) / TM, 1), 256, 0, stream>>>(HS, Wo, bo, out);
}

// Round 5
// 415.292 us; speedup vs baseline: 1.5671x; 1.3569x over previous
//
#include <hip/hip_runtime.h>
#include <math.h>

// Problem constants (from reference)
#define NBLK   4      // NB: blocks
#define NH     8      // H: heads
#define BATCH  2      // B
#define SEQ    1024   // S
#define DIM    512    // D
#define HIDDEN 512    // HID
#define MODF   1.55f  // MOD
#define INV_SQRT_HID 0.04419417382415922f  // 1/sqrt(512)

typedef __bf16 bf16;
typedef __bf16 bf16x4 __attribute__((ext_vector_type(4)));
typedef __bf16 bf16x8 __attribute__((ext_vector_type(8)));
typedef float  floatx4 __attribute__((ext_vector_type(4)));

// ---------------- fp32 vector-GEMM core (R1, PROVEN) ----------------
constexpr int TM = 64, TN = 64, TK = 16;
constexpr int PAD = 4;

template<bool BT>
__device__ __forceinline__ void gemm_tile(
    const float* __restrict__ A, int lda,
    const float* __restrict__ B, int ldb,
    int K, int m0, int n0, float (&acc)[4][4])
{
    __shared__ float As[TK][TM + PAD];
    __shared__ float Bs[TK][TN + PAD];
    const int tid = threadIdx.x;
    const int tx = tid & 15, ty = tid >> 4;

    for (int k0 = 0; k0 < K; k0 += TK) {
        {
            const int m  = tid >> 2;
            const int kv = (tid & 3) << 2;
            const float4 a = *(const float4*)(A + (size_t)(m0 + m) * lda + (k0 + kv));
            As[kv + 0][m] = a.x; As[kv + 1][m] = a.y;
            As[kv + 2][m] = a.z; As[kv + 3][m] = a.w;
        }
        if (BT) {
            const int t  = tid >> 2;
            const int kv = (tid & 3) << 2;
            const float4 b = *(const float4*)(B + (size_t)(n0 + t) * ldb + (k0 + kv));
            Bs[kv + 0][t] = b.x; Bs[kv + 1][t] = b.y;
            Bs[kv + 2][t] = b.z; Bs[kv + 3][t] = b.w;
        } else {
            const int k  = tid >> 4;
            const int nv = (tid & 15) << 2;
            const float4 b = *(const float4*)(B + (size_t)(k0 + k) * ldb + (n0 + nv));
            *(float4*)&Bs[k][nv] = b;
        }
        __syncthreads();

#pragma unroll
        for (int kk = 0; kk < TK; ++kk) {
            const float4 a = *(const float4*)&As[kk][ty << 2];
            const float4 b = *(const float4*)&Bs[kk][tx << 2];
            acc[0][0] += a.x * b.x; acc[0][1] += a.x * b.y; acc[0][2] += a.x * b.z; acc[0][3] += a.x * b.w;
            acc[1][0] += a.y * b.x; acc[1][1] += a.y * b.y; acc[1][2] += a.y * b.z; acc[1][3] += a.y * b.w;
            acc[2][0] += a.z * b.x; acc[2][1] += a.z * b.y; acc[2][2] += a.z * b.z; acc[2][3] += a.z * b.w;
            acc[3][0] += a.w * b.x; acc[3][1] += a.w * b.y; acc[3][2] += a.w * b.z; acc[3][3] += a.w * b.w;
        }
        __syncthreads();
    }
}

// ---------------- bf16 MFMA NT core (PROVEN in R4) ----------------
constexpr int BM = 128, BN = 128, BK = 32;
constexpr int BKP = 40;   // padded LDS K-stride (80 B, 16B-aligned)

__device__ __forceinline__ void mfma_nt(
    const bf16* __restrict__ A, int lda,
    const bf16* __restrict__ B, int ldb,
    int K, int m0, int n0, floatx4 (&acc)[4][4])
{
    __shared__ __align__(16) bf16 As[BM * BKP];
    __shared__ __align__(16) bf16 Bs[BN * BKP];

    const int tid = threadIdx.x;
    const int l   = tid & 63;
    const int w   = tid >> 6;
    const int wr  = (w >> 1) * 64;
    const int wc  = (w & 1) * 64;

    const int srow = tid >> 2;         // 0..63
    const int scol = (tid & 3) * 8;    // 0,8,16,24

    const int fr = l & 15;
    const int fk = (l >> 4) * 8;

    const bf16* Ab = A + (size_t)m0 * lda;
    const bf16* Bb = B + (size_t)n0 * ldb;

    for (int k0 = 0; k0 < K; k0 += BK) {
        const bf16x8 ra0 = *(const bf16x8*)(Ab + (size_t)srow        * lda + k0 + scol);
        const bf16x8 ra1 = *(const bf16x8*)(Ab + (size_t)(srow + 64) * lda + k0 + scol);
        const bf16x8 rb0 = *(const bf16x8*)(Bb + (size_t)srow        * ldb + k0 + scol);
        const bf16x8 rb1 = *(const bf16x8*)(Bb + (size_t)(srow + 64) * ldb + k0 + scol);

        __syncthreads();
        *(bf16x8*)&As[srow        * BKP + scol] = ra0;
        *(bf16x8*)&As[(srow + 64) * BKP + scol] = ra1;
        *(bf16x8*)&Bs[srow        * BKP + scol] = rb0;
        *(bf16x8*)&Bs[(srow + 64) * BKP + scol] = rb1;
        __syncthreads();

        bf16x8 af[4], bg[4];
#pragma unroll
        for (int i = 0; i < 4; ++i)
            af[i] = *(const bf16x8*)&As[(wr + i * 16 + fr) * BKP + fk];
#pragma unroll
        for (int j = 0; j < 4; ++j)
            bg[j] = *(const bf16x8*)&Bs[(wc + j * 16 + fr) * BKP + fk];
#pragma unroll
        for (int i = 0; i < 4; ++i)
#pragma unroll
            for (int j = 0; j < 4; ++j)
                acc[i][j] = __builtin_amdgcn_mfma_f32_16x16x32_bf16(
                    af[i], bg[j], acc[i][j], 0, 0, 0);
    }
}

// ---------------------------------------------------------------------------
// NEW (under test) Prep 1: x fp32 [2048][512] -> xb bf16 same layout
// ---------------------------------------------------------------------------
__global__ __launch_bounds__(256) void xconv_kernel(
    const float* __restrict__ x, bf16* __restrict__ xb)
{
    const int t = blockIdx.x * 256 + threadIdx.x;
    const float4 v = ((const float4*)x)[t];
    bf16x4 o = { (bf16)v.x, (bf16)v.y, (bf16)v.z, (bf16)v.w };
    *(bf16x4*)&xb[(size_t)t * 4] = o;
}

// ---------------------------------------------------------------------------
// NEW (under test) Prep 2: transpose + bf16-cast Wq/Wk/Wv slices.
// z = mat*4 + n; mat: 0=Wq 1=Wk 2=Wv.  dst[h][d] = src[d][h].
// ---------------------------------------------------------------------------
__global__ __launch_bounds__(256) void transpose_w_kernel(
    const float* __restrict__ Wq, const float* __restrict__ Wk,
    const float* __restrict__ Wv,
    bf16* __restrict__ WqT, bf16* __restrict__ WkT, bf16* __restrict__ WvT)
{
    __shared__ float tile[32][33];
    const int z = blockIdx.z;
    const int mat = z >> 2, n = z & 3;
    const float* src; bf16* dst;
    if (mat == 0)      { src = Wq; dst = WqT; }
    else if (mat == 1) { src = Wk; dst = WkT; }
    else               { src = Wv; dst = WvT; }
    src += (size_t)n * 512 * 512;
    dst += (size_t)n * 512 * 512;

    const int tx = threadIdx.x & 31, ty = threadIdx.x >> 5;   // 32 x 8
    const int x0 = blockIdx.x * 32, y0 = blockIdx.y * 32;
#pragma unroll
    for (int r = 0; r < 4; ++r)
        tile[ty + r * 8][tx] = src[(size_t)(y0 + ty + r * 8) * 512 + x0 + tx];
    __syncthreads();
#pragma unroll
    for (int r = 0; r < 4; ++r)
        dst[(size_t)(x0 + ty + r * 8) * 512 + y0 + tx] = (bf16)tile[tx][ty + r * 8];
}

// ---------------------------------------------------------------------------
// NEW (under test): QKV projections via MFMA.  z = which*4 + n.
// C[m][h] = xb[m] . WT[n][h] + bias[h]
// which 0 -> Qh bf16, 1 -> Kh bf16, 2 -> Vb fp32 (R1 layout [m][d])
// Core + C/D mapping are R4-proven; only +bias and store dtype are new.
// ---------------------------------------------------------------------------
__global__ __launch_bounds__(256) void proj_mfma_kernel(
    const bf16* __restrict__ xb,
    const bf16* __restrict__ WqT, const bf16* __restrict__ WkT,
    const bf16* __restrict__ WvT,
    const float* __restrict__ bq, const float* __restrict__ bk,
    const float* __restrict__ bv,
    bf16* __restrict__ Qh, bf16* __restrict__ Kh, float* __restrict__ Vb)
{
    const int z = blockIdx.z;
    const int n = z & 3, which = z >> 2;
    const bf16* WT; const float* bias;
    if (which == 0)      { WT = WqT; bias = bq; }
    else if (which == 1) { WT = WkT; bias = bk; }
    else                 { WT = WvT; bias = bv; }
    WT   += (size_t)n * DIM * HIDDEN;
    bias += (size_t)n * HIDDEN;

    const int m0 = blockIdx.y * BM, n0 = blockIdx.x * BN;
    floatx4 acc[4][4] = {};
    mfma_nt(xb, DIM, WT, DIM, DIM, m0, n0, acc);

    const int l = threadIdx.x & 63, w = threadIdx.x >> 6;
    const int rb = m0 + (w >> 1) * 64 + (l >> 4) * 4;
    const int cb = n0 + (w & 1) * 64 + (l & 15);

    if (which == 2) {
        float* C = Vb + (size_t)n * (BATCH * SEQ) * HIDDEN;
#pragma unroll
        for (int j = 0; j < 4; ++j) {
            const int col = cb + j * 16;
            const float bc = bias[col];
#pragma unroll
            for (int i = 0; i < 4; ++i)
#pragma unroll
                for (int r = 0; r < 4; ++r)
                    C[(size_t)(rb + i * 16 + r) * HIDDEN + col] = acc[i][j][r] + bc;
        }
    } else {
        bf16* C = (which ? Kh : Qh) + (size_t)n * (BATCH * SEQ) * HIDDEN;
#pragma unroll
        for (int j = 0; j < 4; ++j) {
            const int col = cb + j * 16;
            const float bc = bias[col];
#pragma unroll
            for (int i = 0; i < 4; ++i)
#pragma unroll
                for (int r = 0; r < 4; ++r)
                    C[(size_t)(rb + i * 16 + r) * HIDDEN + col] = (bf16)(acc[i][j][r] + bc);
        }
    }
}

// ---------------------------------------------------------------------------
// R4-PROVEN: scores via MFMA: P[z][s][t] = (Q[z][s].K[z][t]) / sqrt(HID)
// ---------------------------------------------------------------------------
__global__ __launch_bounds__(256) void scores_mfma_kernel(
    const bf16* __restrict__ Qh, const bf16* __restrict__ Kh,
    float* __restrict__ P)
{
    const int z = blockIdx.z;
    const bf16* A = Qh + (size_t)z * SEQ * HIDDEN;
    const bf16* B = Kh + (size_t)z * SEQ * HIDDEN;
    float* C = P + (size_t)z * SEQ * SEQ;

    const int m0 = blockIdx.y * BM, n0 = blockIdx.x * BN;
    floatx4 acc[4][4] = {};
    mfma_nt(A, HIDDEN, B, HIDDEN, HIDDEN, m0, n0, acc);

    const int l = threadIdx.x & 63, w = threadIdx.x >> 6;
    const int rb = m0 + (w >> 1) * 64 + (l >> 4) * 4;
    const int cb = n0 + (w & 1) * 64 + (l & 15);
#pragma unroll
    for (int i = 0; i < 4; ++i)
#pragma unroll
        for (int j = 0; j < 4; ++j)
#pragma unroll
            for (int r = 0; r < 4; ++r)
                C[(size_t)(rb + i * 16 + r) * SEQ + cb + j * 16] =
                    acc[i][j][r] * INV_SQRT_HID;
}

// ---------------------------------------------------------------------------
// R1-PROVEN: in-place fp32 softmax-combine over 8 gated heads.
// ---------------------------------------------------------------------------
__global__ __launch_bounds__(256) void softmax_combine_kernel(
    float* __restrict__ P,
    const float* __restrict__ strength, const float* __restrict__ gate)
{
    const int row = blockIdx.x;
    const int n = row >> 11;
    float* prow = P + (size_t)row * SEQ;
    const int tid = threadIdx.x;
    const int wid = tid >> 6, lane = tid & 63;

    float4 v = ((const float4*)prow)[tid];

    float m = fmaxf(fmaxf(v.x, v.y), fmaxf(v.z, v.w));
#pragma unroll
    for (int off = 32; off > 0; off >>= 1) m = fmaxf(m, __shfl_down(m, off));
    __shared__ float redm[4];
    if (lane == 0) redm[wid] = m;
    __syncthreads();
    const float M = fmaxf(fmaxf(redm[0], redm[1]), fmaxf(redm[2], redm[3]));

    float sh[NH], gh[NH];
#pragma unroll
    for (int h = 0; h < NH; ++h) {
        sh[h] = fminf(fmaxf(strength[n * NH * NH + h * NH + h], 0.01f), 1.0f);
        gh[h] = gate[n * NH + h];
    }

    const float e[4] = { v.x - M, v.y - M, v.z - M, v.w - M };
    float E[4][NH];
    float zsum[NH];
#pragma unroll
    for (int h = 0; h < NH; ++h) zsum[h] = 0.f;
#pragma unroll
    for (int i = 0; i < 4; ++i)
#pragma unroll
        for (int h = 0; h < NH; ++h) {
            const float t = __expf(sh[h] * e[i]);
            E[i][h] = t; zsum[h] += t;
        }

#pragma unroll
    for (int h = 0; h < NH; ++h)
#pragma unroll
        for (int off = 32; off > 0; off >>= 1) zsum[h] += __shfl_down(zsum[h], off);
    __shared__ float redz[4][NH];
    if (lane == 0)
#pragma unroll
        for (int h = 0; h < NH; ++h) redz[wid][h] = zsum[h];
    __syncthreads();

    float wgt[NH];
#pragma unroll
    for (int h = 0; h < NH; ++h) {
        const float Z = redz[0][h] + redz[1][h] + redz[2][h] + redz[3][h];
        wgt[h] = gh[h] / Z;
    }

    float c[4];
#pragma unroll
    for (int i = 0; i < 4; ++i) {
        float s = 0.f;
#pragma unroll
        for (int h = 0; h < NH; ++h) s += wgt[h] * E[i][h];
        c[i] = s;
    }
    ((float4*)prow)[tid] = make_float4(c[0], c[1], c[2], c[3]);
}

// ---------------------------------------------------------------------------
// R1-PROVEN: HS[z][s][d] = P[z] @ V[z]  (fp32)
// ---------------------------------------------------------------------------
__global__ __launch_bounds__(256) void pv_kernel(
    const float* __restrict__ P, const float* __restrict__ Vb,
    float* __restrict__ HS)
{
    const int z = blockIdx.z;
    const float* Ap = P + (size_t)z * SEQ * SEQ;
    const float* Bv = Vb + (size_t)z * SEQ * HIDDEN;
    float* C = HS + (size_t)z * SEQ * HIDDEN;

    const int m0 = blockIdx.y * TM, n0 = blockIdx.x * TN;
    float acc[4][4] = {};
    gemm_tile<false>(Ap, SEQ, Bv, HIDDEN, SEQ, m0, n0, acc);

    const int tx = threadIdx.x & 15, ty = threadIdx.x >> 4;
    const int c = n0 + (tx << 2);
#pragma unroll
    for (int i = 0; i < 4; ++i) {
        const int r = m0 + (ty << 2) + i;
        *(float4*)(C + (size_t)r * HIDDEN + c) =
            make_float4(acc[i][0], acc[i][1], acc[i][2], acc[i][3]);
    }
}

// ---------------------------------------------------------------------------
// R1-PROVEN: out[m][o] = MOD*(sum_n HS[n][m].Wo[n][:,o] + sum_n bo)  (fp32)
// ---------------------------------------------------------------------------
__global__ __launch_bounds__(256) void out_kernel(
    const float* __restrict__ HS, const float* __restrict__ Wo,
    const float* __restrict__ bo, float* __restrict__ out)
{
    const int m0 = blockIdx.y * TM, n0 = blockIdx.x * TN;
    float acc[4][4] = {};
#pragma unroll
    for (int n = 0; n < NBLK; ++n)
        gemm_tile<false>(HS + (size_t)n * BATCH * SEQ * HIDDEN, HIDDEN,
                         Wo + (size_t)n * HIDDEN * DIM, DIM,
                         HIDDEN, m0, n0, acc);

    const int tx = threadIdx.x & 15, ty = threadIdx.x >> 4;
    const int c = n0 + (tx << 2);
    float bsum[4];
#pragma unroll
    for (int j = 0; j < 4; ++j) {
        float s = 0.f;
#pragma unroll
        for (int n = 0; n < NBLK; ++n) s += bo[n * DIM + c + j];
        bsum[j] = s;
    }
#pragma unroll
    for (int i = 0; i < 4; ++i) {
        const int r = m0 + (ty << 2) + i;
        *(float4*)(out + (size_t)r * DIM + c) =
            make_float4((acc[i][0] + bsum[0]) * MODF, (acc[i][1] + bsum[1]) * MODF,
                        (acc[i][2] + bsum[2]) * MODF, (acc[i][3] + bsum[3]) * MODF);
    }
}

// ---------------------------------------------------------------------------
extern "C" void kernel_launch(void* const* d_in, const int* in_sizes, int n_in,
                              void* d_out, int out_size, void* d_ws, size_t ws_size,
                              hipStream_t stream) {
    const float* x        = (const float*)d_in[0];
    const float* Wq       = (const float*)d_in[1];
    const float* bq       = (const float*)d_in[2];
    const float* Wk       = (const float*)d_in[3];
    const float* bk       = (const float*)d_in[4];
    const float* Wv       = (const float*)d_in[5];
    const float* bv       = (const float*)d_in[6];
    const float* Wo       = (const float*)d_in[7];
    const float* bo       = (const float*)d_in[8];
    const float* strength = (const float*)d_in[9];
    const float* gate     = (const float*)d_in[10];
    float* out = (float*)d_out;

    // workspace (MiB offsets), total 72 MiB (< proven 80):
    //   xb  [0,2) | WqT [2,4) | WkT [4,6) | WvT [6,8)
    //   Qh  [8,16) | Kh [16,24) | Vb fp32 [24,40) | Pf fp32 [40,72)
    //   HS fp32 aliases [8,24) (Qh/Kh dead after scores)
    char* ws = (char*)d_ws;
    bf16*  xb  = (bf16*)(ws);
    bf16*  WqT = (bf16*)(ws + (2u << 20));
    bf16*  WkT = (bf16*)(ws + (4u << 20));
    bf16*  WvT = (bf16*)(ws + (6u << 20));
    bf16*  Qh  = (bf16*)(ws + (8u << 20));
    bf16*  Kh  = (bf16*)(ws + (16u << 20));
    float* Vb  = (float*)(ws + (24u << 20));
    float* Pf  = (float*)(ws + (40u << 20));
    float* HS  = (float*)(ws + (8u << 20));   // alias over dead Qh/Kh

    // prep
    xconv_kernel<<<dim3((BATCH * SEQ * DIM) / 1024), 256, 0, stream>>>(x, xb);
    transpose_w_kernel<<<dim3(16, 16, 12), 256, 0, stream>>>(
        Wq, Wk, Wv, WqT, WkT, WvT);

    // 1) QKV projections via MFMA: grid (4, 16, 12)
    proj_mfma_kernel<<<dim3(HIDDEN / BN, (BATCH * SEQ) / BM, 3 * NBLK), 256, 0, stream>>>(
        xb, WqT, WkT, WvT, bq, bk, bv, Qh, Kh, Vb);

    // 2) scores via MFMA: grid (8, 8, 8)
    scores_mfma_kernel<<<dim3(SEQ / BN, SEQ / BM, NBLK * BATCH), 256, 0, stream>>>(
        Qh, Kh, Pf);

    // 3) softmax-combine in place (fp32)
    softmax_combine_kernel<<<dim3(NBLK * BATCH * SEQ), 256, 0, stream>>>(
        Pf, strength, gate);

    // 4) head_sum = P @ V (fp32)
    pv_kernel<<<dim3(HIDDEN / TN, SEQ / TM, NBLK * BATCH), 256, 0, stream>>>(Pf, Vb, HS);

    // 5) output projection (fp32)
    out_kernel<<<dim3(DIM / TN, (BATCH * SEQ) / TM, 1), 256, 0, stream>>>(HS, Wo, bo, out);
}

// Round 6
// 324.095 us; speedup vs baseline: 2.0081x; 1.2814x over previous
//
#include <hip/hip_runtime.h>
#include <math.h>

// Problem constants (from reference)
#define NBLK   4      // NB: blocks
#define NH     8      // H: heads
#define BATCH  2      // B
#define SEQ    1024   // S
#define DIM    512    // D
#define HIDDEN 512    // HID
#define MODF   1.55f  // MOD
#define INV_SQRT_HID 0.04419417382415922f  // 1/sqrt(512)

typedef __bf16 bf16;
typedef __bf16 bf16x4 __attribute__((ext_vector_type(4)));
typedef __bf16 bf16x8 __attribute__((ext_vector_type(8)));
typedef float  floatx4 __attribute__((ext_vector_type(4)));

// ---------------- fp32 vector-GEMM core (R1, PROVEN) ----------------
constexpr int TM = 64, TN = 64, TK = 16;
constexpr int PAD = 4;

template<bool BT>
__device__ __forceinline__ void gemm_tile(
    const float* __restrict__ A, int lda,
    const float* __restrict__ B, int ldb,
    int K, int m0, int n0, float (&acc)[4][4])
{
    __shared__ float As[TK][TM + PAD];
    __shared__ float Bs[TK][TN + PAD];
    const int tid = threadIdx.x;
    const int tx = tid & 15, ty = tid >> 4;

    for (int k0 = 0; k0 < K; k0 += TK) {
        {
            const int m  = tid >> 2;
            const int kv = (tid & 3) << 2;
            const float4 a = *(const float4*)(A + (size_t)(m0 + m) * lda + (k0 + kv));
            As[kv + 0][m] = a.x; As[kv + 1][m] = a.y;
            As[kv + 2][m] = a.z; As[kv + 3][m] = a.w;
        }
        if (BT) {
            const int t  = tid >> 2;
            const int kv = (tid & 3) << 2;
            const float4 b = *(const float4*)(B + (size_t)(n0 + t) * ldb + (k0 + kv));
            Bs[kv + 0][t] = b.x; Bs[kv + 1][t] = b.y;
            Bs[kv + 2][t] = b.z; Bs[kv + 3][t] = b.w;
        } else {
            const int k  = tid >> 4;
            const int nv = (tid & 15) << 2;
            const float4 b = *(const float4*)(B + (size_t)(k0 + k) * ldb + (n0 + nv));
            *(float4*)&Bs[k][nv] = b;
        }
        __syncthreads();

#pragma unroll
        for (int kk = 0; kk < TK; ++kk) {
            const float4 a = *(const float4*)&As[kk][ty << 2];
            const float4 b = *(const float4*)&Bs[kk][tx << 2];
            acc[0][0] += a.x * b.x; acc[0][1] += a.x * b.y; acc[0][2] += a.x * b.z; acc[0][3] += a.x * b.w;
            acc[1][0] += a.y * b.x; acc[1][1] += a.y * b.y; acc[1][2] += a.y * b.z; acc[1][3] += a.y * b.w;
            acc[2][0] += a.z * b.x; acc[2][1] += a.z * b.y; acc[2][2] += a.z * b.z; acc[2][3] += a.z * b.w;
            acc[3][0] += a.w * b.x; acc[3][1] += a.w * b.y; acc[3][2] += a.w * b.z; acc[3][3] += a.w * b.w;
        }
        __syncthreads();
    }
}

// ---------------- bf16 MFMA NT core (PROVEN in R4/R5) ----------------
constexpr int BM = 128, BN = 128, BK = 32;
constexpr int BKP = 40;   // padded LDS K-stride (80 B, 16B-aligned)

__device__ __forceinline__ void mfma_nt(
    const bf16* __restrict__ A, int lda,
    const bf16* __restrict__ B, int ldb,
    int K, int m0, int n0, floatx4 (&acc)[4][4])
{
    __shared__ __align__(16) bf16 As[BM * BKP];
    __shared__ __align__(16) bf16 Bs[BN * BKP];

    const int tid = threadIdx.x;
    const int l   = tid & 63;
    const int w   = tid >> 6;
    const int wr  = (w >> 1) * 64;
    const int wc  = (w & 1) * 64;

    const int srow = tid >> 2;         // 0..63
    const int scol = (tid & 3) * 8;    // 0,8,16,24

    const int fr = l & 15;
    const int fk = (l >> 4) * 8;

    const bf16* Ab = A + (size_t)m0 * lda;
    const bf16* Bb = B + (size_t)n0 * ldb;

    for (int k0 = 0; k0 < K; k0 += BK) {
        const bf16x8 ra0 = *(const bf16x8*)(Ab + (size_t)srow        * lda + k0 + scol);
        const bf16x8 ra1 = *(const bf16x8*)(Ab + (size_t)(srow + 64) * lda + k0 + scol);
        const bf16x8 rb0 = *(const bf16x8*)(Bb + (size_t)srow        * ldb + k0 + scol);
        const bf16x8 rb1 = *(const bf16x8*)(Bb + (size_t)(srow + 64) * ldb + k0 + scol);

        __syncthreads();
        *(bf16x8*)&As[srow        * BKP + scol] = ra0;
        *(bf16x8*)&As[(srow + 64) * BKP + scol] = ra1;
        *(bf16x8*)&Bs[srow        * BKP + scol] = rb0;
        *(bf16x8*)&Bs[(srow + 64) * BKP + scol] = rb1;
        __syncthreads();

        bf16x8 af[4], bg[4];
#pragma unroll
        for (int i = 0; i < 4; ++i)
            af[i] = *(const bf16x8*)&As[(wr + i * 16 + fr) * BKP + fk];
#pragma unroll
        for (int j = 0; j < 4; ++j)
            bg[j] = *(const bf16x8*)&Bs[(wc + j * 16 + fr) * BKP + fk];
#pragma unroll
        for (int i = 0; i < 4; ++i)
#pragma unroll
            for (int j = 0; j < 4; ++j)
                acc[i][j] = __builtin_amdgcn_mfma_f32_16x16x32_bf16(
                    af[i], bg[j], acc[i][j], 0, 0, 0);
    }
}

// ---------------------------------------------------------------------------
// PROVEN Prep 1: x fp32 [2048][512] -> xb bf16 same layout
// ---------------------------------------------------------------------------
__global__ __launch_bounds__(256) void xconv_kernel(
    const float* __restrict__ x, bf16* __restrict__ xb)
{
    const int t = blockIdx.x * 256 + threadIdx.x;
    const float4 v = ((const float4*)x)[t];
    bf16x4 o = { (bf16)v.x, (bf16)v.y, (bf16)v.z, (bf16)v.w };
    *(bf16x4*)&xb[(size_t)t * 4] = o;
}

// ---------------------------------------------------------------------------
// PROVEN (structure) Prep 2: transpose + bf16-cast weight slices.
// z = mat*4 + n; mat: 0=Wq 1=Wk 2=Wv 3=Wo (mat==3 new, identical structure).
// dst[h][d] = src[d][h].
// ---------------------------------------------------------------------------
__global__ __launch_bounds__(256) void transpose_w_kernel(
    const float* __restrict__ Wq, const float* __restrict__ Wk,
    const float* __restrict__ Wv, const float* __restrict__ Wo,
    bf16* __restrict__ WqT, bf16* __restrict__ WkT,
    bf16* __restrict__ WvT, bf16* __restrict__ WoT)
{
    __shared__ float tile[32][33];
    const int z = blockIdx.z;
    const int mat = z >> 2, n = z & 3;
    const float* src; bf16* dst;
    if (mat == 0)      { src = Wq; dst = WqT; }
    else if (mat == 1) { src = Wk; dst = WkT; }
    else if (mat == 2) { src = Wv; dst = WvT; }
    else               { src = Wo; dst = WoT; }
    src += (size_t)n * 512 * 512;
    dst += (size_t)n * 512 * 512;

    const int tx = threadIdx.x & 31, ty = threadIdx.x >> 5;   // 32 x 8
    const int x0 = blockIdx.x * 32, y0 = blockIdx.y * 32;
#pragma unroll
    for (int r = 0; r < 4; ++r)
        tile[ty + r * 8][tx] = src[(size_t)(y0 + ty + r * 8) * 512 + x0 + tx];
    __syncthreads();
#pragma unroll
    for (int r = 0; r < 4; ++r)
        dst[(size_t)(x0 + ty + r * 8) * 512 + y0 + tx] = (bf16)tile[tx][ty + r * 8];
}

// ---------------------------------------------------------------------------
// PROVEN: QKV projections via MFMA.  z = which*4 + n.
// which 0 -> Qh bf16, 1 -> Kh bf16, 2 -> Vb fp32 ([m][d])
// ---------------------------------------------------------------------------
__global__ __launch_bounds__(256) void proj_mfma_kernel(
    const bf16* __restrict__ xb,
    const bf16* __restrict__ WqT, const bf16* __restrict__ WkT,
    const bf16* __restrict__ WvT,
    const float* __restrict__ bq, const float* __restrict__ bk,
    const float* __restrict__ bv,
    bf16* __restrict__ Qh, bf16* __restrict__ Kh, float* __restrict__ Vb)
{
    const int z = blockIdx.z;
    const int n = z & 3, which = z >> 2;
    const bf16* WT; const float* bias;
    if (which == 0)      { WT = WqT; bias = bq; }
    else if (which == 1) { WT = WkT; bias = bk; }
    else                 { WT = WvT; bias = bv; }
    WT   += (size_t)n * DIM * HIDDEN;
    bias += (size_t)n * HIDDEN;

    const int m0 = blockIdx.y * BM, n0 = blockIdx.x * BN;
    floatx4 acc[4][4] = {};
    mfma_nt(xb, DIM, WT, DIM, DIM, m0, n0, acc);

    const int l = threadIdx.x & 63, w = threadIdx.x >> 6;
    const int rb = m0 + (w >> 1) * 64 + (l >> 4) * 4;
    const int cb = n0 + (w & 1) * 64 + (l & 15);

    if (which == 2) {
        float* C = Vb + (size_t)n * (BATCH * SEQ) * HIDDEN;
#pragma unroll
        for (int j = 0; j < 4; ++j) {
            const int col = cb + j * 16;
            const float bc = bias[col];
#pragma unroll
            for (int i = 0; i < 4; ++i)
#pragma unroll
                for (int r = 0; r < 4; ++r)
                    C[(size_t)(rb + i * 16 + r) * HIDDEN + col] = acc[i][j][r] + bc;
        }
    } else {
        bf16* C = (which ? Kh : Qh) + (size_t)n * (BATCH * SEQ) * HIDDEN;
#pragma unroll
        for (int j = 0; j < 4; ++j) {
            const int col = cb + j * 16;
            const float bc = bias[col];
#pragma unroll
            for (int i = 0; i < 4; ++i)
#pragma unroll
                for (int r = 0; r < 4; ++r)
                    C[(size_t)(rb + i * 16 + r) * HIDDEN + col] = (bf16)(acc[i][j][r] + bc);
        }
    }
}

// ---------------------------------------------------------------------------
// PROVEN: scores via MFMA: P[z][s][t] = (Q[z][s].K[z][t]) / sqrt(HID)
// ---------------------------------------------------------------------------
__global__ __launch_bounds__(256) void scores_mfma_kernel(
    const bf16* __restrict__ Qh, const bf16* __restrict__ Kh,
    float* __restrict__ P)
{
    const int z = blockIdx.z;
    const bf16* A = Qh + (size_t)z * SEQ * HIDDEN;
    const bf16* B = Kh + (size_t)z * SEQ * HIDDEN;
    float* C = P + (size_t)z * SEQ * SEQ;

    const int m0 = blockIdx.y * BM, n0 = blockIdx.x * BN;
    floatx4 acc[4][4] = {};
    mfma_nt(A, HIDDEN, B, HIDDEN, HIDDEN, m0, n0, acc);

    const int l = threadIdx.x & 63, w = threadIdx.x >> 6;
    const int rb = m0 + (w >> 1) * 64 + (l >> 4) * 4;
    const int cb = n0 + (w & 1) * 64 + (l & 15);
#pragma unroll
    for (int i = 0; i < 4; ++i)
#pragma unroll
        for (int j = 0; j < 4; ++j)
#pragma unroll
            for (int r = 0; r < 4; ++r)
                C[(size_t)(rb + i * 16 + r) * SEQ + cb + j * 16] =
                    acc[i][j][r] * INV_SQRT_HID;
}

// ---------------------------------------------------------------------------
// PROVEN: in-place fp32 softmax-combine over 8 gated heads.
// ---------------------------------------------------------------------------
__global__ __launch_bounds__(256) void softmax_combine_kernel(
    float* __restrict__ P,
    const float* __restrict__ strength, const float* __restrict__ gate)
{
    const int row = blockIdx.x;
    const int n = row >> 11;
    float* prow = P + (size_t)row * SEQ;
    const int tid = threadIdx.x;
    const int wid = tid >> 6, lane = tid & 63;

    float4 v = ((const float4*)prow)[tid];

    float m = fmaxf(fmaxf(v.x, v.y), fmaxf(v.z, v.w));
#pragma unroll
    for (int off = 32; off > 0; off >>= 1) m = fmaxf(m, __shfl_down(m, off));
    __shared__ float redm[4];
    if (lane == 0) redm[wid] = m;
    __syncthreads();
    const float M = fmaxf(fmaxf(redm[0], redm[1]), fmaxf(redm[2], redm[3]));

    float sh[NH], gh[NH];
#pragma unroll
    for (int h = 0; h < NH; ++h) {
        sh[h] = fminf(fmaxf(strength[n * NH * NH + h * NH + h], 0.01f), 1.0f);
        gh[h] = gate[n * NH + h];
    }

    const float e[4] = { v.x - M, v.y - M, v.z - M, v.w - M };
    float E[4][NH];
    float zsum[NH];
#pragma unroll
    for (int h = 0; h < NH; ++h) zsum[h] = 0.f;
#pragma unroll
    for (int i = 0; i < 4; ++i)
#pragma unroll
        for (int h = 0; h < NH; ++h) {
            const float t = __expf(sh[h] * e[i]);
            E[i][h] = t; zsum[h] += t;
        }

#pragma unroll
    for (int h = 0; h < NH; ++h)
#pragma unroll
        for (int off = 32; off > 0; off >>= 1) zsum[h] += __shfl_down(zsum[h], off);
    __shared__ float redz[4][NH];
    if (lane == 0)
#pragma unroll
        for (int h = 0; h < NH; ++h) redz[wid][h] = zsum[h];
    __syncthreads();

    float wgt[NH];
#pragma unroll
    for (int h = 0; h < NH; ++h) {
        const float Z = redz[0][h] + redz[1][h] + redz[2][h] + redz[3][h];
        wgt[h] = gh[h] / Z;
    }

    float c[4];
#pragma unroll
    for (int i = 0; i < 4; ++i) {
        float s = 0.f;
#pragma unroll
        for (int h = 0; h < NH; ++h) s += wgt[h] * E[i][h];
        c[i] = s;
    }
    ((float4*)prow)[tid] = make_float4(c[0], c[1], c[2], c[3]);
}

// ---------------------------------------------------------------------------
// PROVEN core + R4-proven bf16 store: HS[z][s][d] = P[z] @ V[z], bf16 out.
// ---------------------------------------------------------------------------
__global__ __launch_bounds__(256) void pv_kernel(
    const float* __restrict__ P, const float* __restrict__ Vb,
    bf16* __restrict__ HS)
{
    const int z = blockIdx.z;
    const float* Ap = P + (size_t)z * SEQ * SEQ;
    const float* Bv = Vb + (size_t)z * SEQ * HIDDEN;
    bf16* C = HS + (size_t)z * SEQ * HIDDEN;

    const int m0 = blockIdx.y * TM, n0 = blockIdx.x * TN;
    float acc[4][4] = {};
    gemm_tile<false>(Ap, SEQ, Bv, HIDDEN, SEQ, m0, n0, acc);

    const int tx = threadIdx.x & 15, ty = threadIdx.x >> 4;
    const int c = n0 + (tx << 2);
#pragma unroll
    for (int i = 0; i < 4; ++i) {
        const int r = m0 + (ty << 2) + i;
        bf16x4 o = { (bf16)acc[i][0], (bf16)acc[i][1],
                     (bf16)acc[i][2], (bf16)acc[i][3] };
        *(bf16x4*)&C[(size_t)r * HIDDEN + c] = o;
    }
}

// ---------------------------------------------------------------------------
// NEW (under test — the n-loop cluster): out projection via MFMA.
// out[m][o] = MOD * ( sum_n HS[n][m] . WoT[n][o] + sum_n bo[n][o] )
// 4x mfma_nt accumulation into one acc (function-scope LDS is one allocation;
// loop-top __syncthreads covers WAR between calls). Bias epilogue = R5-proven.
// ---------------------------------------------------------------------------
__global__ __launch_bounds__(256) void out_mfma_kernel(
    const bf16* __restrict__ HS, const bf16* __restrict__ WoT,
    const float* __restrict__ bo, float* __restrict__ out)
{
    const int m0 = blockIdx.y * BM, n0 = blockIdx.x * BN;
    floatx4 acc[4][4] = {};
#pragma unroll
    for (int n = 0; n < NBLK; ++n)
        mfma_nt(HS + (size_t)n * (BATCH * SEQ) * HIDDEN, HIDDEN,
                WoT + (size_t)n * HIDDEN * DIM, HIDDEN,
                HIDDEN, m0, n0, acc);

    const int l = threadIdx.x & 63, w = threadIdx.x >> 6;
    const int rb = m0 + (w >> 1) * 64 + (l >> 4) * 4;
    const int cb = n0 + (w & 1) * 64 + (l & 15);
#pragma unroll
    for (int j = 0; j < 4; ++j) {
        const int col = cb + j * 16;
        float bs = 0.f;
#pragma unroll
        for (int n = 0; n < NBLK; ++n) bs += bo[n * DIM + col];
#pragma unroll
        for (int i = 0; i < 4; ++i)
#pragma unroll
            for (int r = 0; r < 4; ++r)
                out[(size_t)(rb + i * 16 + r) * DIM + col] =
                    (acc[i][j][r] + bs) * MODF;
    }
}

// ---------------------------------------------------------------------------
extern "C" void kernel_launch(void* const* d_in, const int* in_sizes, int n_in,
                              void* d_out, int out_size, void* d_ws, size_t ws_size,
                              hipStream_t stream) {
    const float* x        = (const float*)d_in[0];
    const float* Wq       = (const float*)d_in[1];
    const float* bq       = (const float*)d_in[2];
    const float* Wk       = (const float*)d_in[3];
    const float* bk       = (const float*)d_in[4];
    const float* Wv       = (const float*)d_in[5];
    const float* bv       = (const float*)d_in[6];
    const float* Wo       = (const float*)d_in[7];
    const float* bo       = (const float*)d_in[8];
    const float* strength = (const float*)d_in[9];
    const float* gate     = (const float*)d_in[10];
    float* out = (float*)d_out;

    // workspace (MiB offsets), total 74 MiB (<= proven 80):
    //   xb  [0,2) | WqT [2,4) | WkT [4,6) | WvT [6,8) | WoT [8,10)
    //   Qh  [10,18) | Kh [18,26) | Vb fp32 [26,42) | Pf fp32 [42,74)
    //   HS bf16 (8 MiB) aliases [10,18) (Qh dead after scores)
    char* ws = (char*)d_ws;
    bf16*  xb  = (bf16*)(ws);
    bf16*  WqT = (bf16*)(ws + (2u  << 20));
    bf16*  WkT = (bf16*)(ws + (4u  << 20));
    bf16*  WvT = (bf16*)(ws + (6u  << 20));
    bf16*  WoT = (bf16*)(ws + (8u  << 20));
    bf16*  Qh  = (bf16*)(ws + (10u << 20));
    bf16*  Kh  = (bf16*)(ws + (18u << 20));
    float* Vb  = (float*)(ws + (26u << 20));
    float* Pf  = (float*)(ws + (42u << 20));
    bf16*  HS  = (bf16*)(ws + (10u << 20));   // alias over dead Qh

    // prep
    xconv_kernel<<<dim3((BATCH * SEQ * DIM) / 1024), 256, 0, stream>>>(x, xb);
    transpose_w_kernel<<<dim3(16, 16, 16), 256, 0, stream>>>(
        Wq, Wk, Wv, Wo, WqT, WkT, WvT, WoT);

    // 1) QKV projections via MFMA: grid (4, 16, 12)
    proj_mfma_kernel<<<dim3(HIDDEN / BN, (BATCH * SEQ) / BM, 3 * NBLK), 256, 0, stream>>>(
        xb, WqT, WkT, WvT, bq, bk, bv, Qh, Kh, Vb);

    // 2) scores via MFMA: grid (8, 8, 8)
    scores_mfma_kernel<<<dim3(SEQ / BN, SEQ / BM, NBLK * BATCH), 256, 0, stream>>>(
        Qh, Kh, Pf);

    // 3) softmax-combine in place (fp32)
    softmax_combine_kernel<<<dim3(NBLK * BATCH * SEQ), 256, 0, stream>>>(
        Pf, strength, gate);

    // 4) head_sum = P @ V (fp32 core, bf16 store): grid (8, 16, 8)
    pv_kernel<<<dim3(HIDDEN / TN, SEQ / TM, NBLK * BATCH), 256, 0, stream>>>(Pf, Vb, HS);

    // 5) output projection via MFMA: grid (4, 16)
    out_mfma_kernel<<<dim3(DIM / BN, (BATCH * SEQ) / BM, 1), 256, 0, stream>>>(
        HS, WoT, bo, out);
}

// Round 7
// 231.162 us; speedup vs baseline: 2.8154x; 1.4020x over previous
//
#include <hip/hip_runtime.h>
#include <math.h>

// Problem constants (from reference)
#define NBLK   4      // NB: blocks
#define NH     8      // H: heads
#define BATCH  2      // B
#define SEQ    1024   // S
#define DIM    512    // D
#define HIDDEN 512    // HID
#define MODF   1.55f  // MOD
#define INV_SQRT_HID 0.04419417382415922f  // 1/sqrt(512)

typedef __bf16 bf16;
typedef __bf16 bf16x4 __attribute__((ext_vector_type(4)));
typedef __bf16 bf16x8 __attribute__((ext_vector_type(8)));
typedef float  floatx4 __attribute__((ext_vector_type(4)));

// ---------------- bf16 MFMA NT core (PROVEN R4/R5/R6) ----------------
constexpr int BM = 128, BN = 128, BK = 32;
constexpr int BKP = 40;   // padded LDS K-stride (80 B, 16B-aligned)

__device__ __forceinline__ void mfma_nt(
    const bf16* __restrict__ A, int lda,
    const bf16* __restrict__ B, int ldb,
    int K, int m0, int n0, floatx4 (&acc)[4][4])
{
    __shared__ __align__(16) bf16 As[BM * BKP];
    __shared__ __align__(16) bf16 Bs[BN * BKP];

    const int tid = threadIdx.x;
    const int l   = tid & 63;
    const int w   = tid >> 6;
    const int wr  = (w >> 1) * 64;
    const int wc  = (w & 1) * 64;

    const int srow = tid >> 2;         // 0..63
    const int scol = (tid & 3) * 8;    // 0,8,16,24

    const int fr = l & 15;
    const int fk = (l >> 4) * 8;

    const bf16* Ab = A + (size_t)m0 * lda;
    const bf16* Bb = B + (size_t)n0 * ldb;

    for (int k0 = 0; k0 < K; k0 += BK) {
        const bf16x8 ra0 = *(const bf16x8*)(Ab + (size_t)srow        * lda + k0 + scol);
        const bf16x8 ra1 = *(const bf16x8*)(Ab + (size_t)(srow + 64) * lda + k0 + scol);
        const bf16x8 rb0 = *(const bf16x8*)(Bb + (size_t)srow        * ldb + k0 + scol);
        const bf16x8 rb1 = *(const bf16x8*)(Bb + (size_t)(srow + 64) * ldb + k0 + scol);

        __syncthreads();
        *(bf16x8*)&As[srow        * BKP + scol] = ra0;
        *(bf16x8*)&As[(srow + 64) * BKP + scol] = ra1;
        *(bf16x8*)&Bs[srow        * BKP + scol] = rb0;
        *(bf16x8*)&Bs[(srow + 64) * BKP + scol] = rb1;
        __syncthreads();

        bf16x8 af[4], bg[4];
#pragma unroll
        for (int i = 0; i < 4; ++i)
            af[i] = *(const bf16x8*)&As[(wr + i * 16 + fr) * BKP + fk];
#pragma unroll
        for (int j = 0; j < 4; ++j)
            bg[j] = *(const bf16x8*)&Bs[(wc + j * 16 + fr) * BKP + fk];
#pragma unroll
        for (int i = 0; i < 4; ++i)
#pragma unroll
            for (int j = 0; j < 4; ++j)
                acc[i][j] = __builtin_amdgcn_mfma_f32_16x16x32_bf16(
                    af[i], bg[j], acc[i][j], 0, 0, 0);
    }
}

// ---------------------------------------------------------------------------
// PROVEN Prep 1: x fp32 [2048][512] -> xb bf16 same layout
// ---------------------------------------------------------------------------
__global__ __launch_bounds__(256) void xconv_kernel(
    const float* __restrict__ x, bf16* __restrict__ xb)
{
    const int t = blockIdx.x * 256 + threadIdx.x;
    const float4 v = ((const float4*)x)[t];
    bf16x4 o = { (bf16)v.x, (bf16)v.y, (bf16)v.z, (bf16)v.w };
    *(bf16x4*)&xb[(size_t)t * 4] = o;
}

// ---------------------------------------------------------------------------
// PROVEN Prep 2: transpose + bf16-cast weight slices (fp32 in, bf16 out).
// z = mat*4 + n; mat: 0=Wq 1=Wk 2=Wv 3=Wo.  dst[h][d] = src[d][h]. 512x512.
// ---------------------------------------------------------------------------
__global__ __launch_bounds__(256) void transpose_w_kernel(
    const float* __restrict__ Wq, const float* __restrict__ Wk,
    const float* __restrict__ Wv, const float* __restrict__ Wo,
    bf16* __restrict__ WqT, bf16* __restrict__ WkT,
    bf16* __restrict__ WvT, bf16* __restrict__ WoT)
{
    __shared__ float tile[32][33];
    const int z = blockIdx.z;
    const int mat = z >> 2, n = z & 3;
    const float* src; bf16* dst;
    if (mat == 0)      { src = Wq; dst = WqT; }
    else if (mat == 1) { src = Wk; dst = WkT; }
    else if (mat == 2) { src = Wv; dst = WvT; }
    else               { src = Wo; dst = WoT; }
    src += (size_t)n * 512 * 512;
    dst += (size_t)n * 512 * 512;

    const int tx = threadIdx.x & 31, ty = threadIdx.x >> 5;   // 32 x 8
    const int x0 = blockIdx.x * 32, y0 = blockIdx.y * 32;
#pragma unroll
    for (int r = 0; r < 4; ++r)
        tile[ty + r * 8][tx] = src[(size_t)(y0 + ty + r * 8) * 512 + x0 + tx];
    __syncthreads();
#pragma unroll
    for (int r = 0; r < 4; ++r)
        dst[(size_t)(x0 + ty + r * 8) * 512 + y0 + tx] = (bf16)tile[tx][ty + r * 8];
}

// ---------------------------------------------------------------------------
// NEW (proven structure, new dims): bf16 transpose of V per z-slice.
// src = Vm[z] : [SEQ][HIDDEN] (ld 512) -> dst = Vt[z] : [HIDDEN][SEQ] (ld 1024)
// dst[d][t] = src[t][d].
// ---------------------------------------------------------------------------
__global__ __launch_bounds__(256) void transpose_v_kernel(
    const bf16* __restrict__ Vm, bf16* __restrict__ Vt)
{
    __shared__ float tile[32][33];
    const int z = blockIdx.z;
    const bf16* src = Vm + (size_t)z * SEQ * HIDDEN;
    bf16*       dst = Vt + (size_t)z * HIDDEN * SEQ;

    const int tx = threadIdx.x & 31, ty = threadIdx.x >> 5;   // 32 x 8
    const int x0 = blockIdx.x * 32;   // over HIDDEN (src cols)
    const int y0 = blockIdx.y * 32;   // over SEQ (src rows)
#pragma unroll
    for (int r = 0; r < 4; ++r)
        tile[ty + r * 8][tx] = (float)src[(size_t)(y0 + ty + r * 8) * HIDDEN + x0 + tx];
    __syncthreads();
#pragma unroll
    for (int r = 0; r < 4; ++r)
        dst[(size_t)(x0 + ty + r * 8) * SEQ + y0 + tx] = (bf16)tile[tx][ty + r * 8];
}

// ---------------------------------------------------------------------------
// PROVEN: QKV projections via MFMA.  z = which*4 + n.  All outputs bf16 [m][h]
// (identical proven store path for Q, K and V).
// ---------------------------------------------------------------------------
__global__ __launch_bounds__(256) void proj_mfma_kernel(
    const bf16* __restrict__ xb,
    const bf16* __restrict__ WqT, const bf16* __restrict__ WkT,
    const bf16* __restrict__ WvT,
    const float* __restrict__ bq, const float* __restrict__ bk,
    const float* __restrict__ bv,
    bf16* __restrict__ Qh, bf16* __restrict__ Kh, bf16* __restrict__ Vm)
{
    const int z = blockIdx.z;
    const int n = z & 3, which = z >> 2;
    const bf16* WT; const float* bias; bf16* Cb;
    if (which == 0)      { WT = WqT; bias = bq; Cb = Qh; }
    else if (which == 1) { WT = WkT; bias = bk; Cb = Kh; }
    else                 { WT = WvT; bias = bv; Cb = Vm; }
    WT   += (size_t)n * DIM * HIDDEN;
    bias += (size_t)n * HIDDEN;
    bf16* C = Cb + (size_t)n * (BATCH * SEQ) * HIDDEN;

    const int m0 = blockIdx.y * BM, n0 = blockIdx.x * BN;
    floatx4 acc[4][4] = {};
    mfma_nt(xb, DIM, WT, DIM, DIM, m0, n0, acc);

    const int l = threadIdx.x & 63, w = threadIdx.x >> 6;
    const int rb = m0 + (w >> 1) * 64 + (l >> 4) * 4;
    const int cb = n0 + (w & 1) * 64 + (l & 15);
#pragma unroll
    for (int j = 0; j < 4; ++j) {
        const int col = cb + j * 16;
        const float bc = bias[col];
#pragma unroll
        for (int i = 0; i < 4; ++i)
#pragma unroll
            for (int r = 0; r < 4; ++r)
                C[(size_t)(rb + i * 16 + r) * HIDDEN + col] = (bf16)(acc[i][j][r] + bc);
    }
}

// ---------------------------------------------------------------------------
// PROVEN: scores via MFMA: P[z][s][t] = (Q[z][s].K[z][t]) / sqrt(HID)
// ---------------------------------------------------------------------------
__global__ __launch_bounds__(256) void scores_mfma_kernel(
    const bf16* __restrict__ Qh, const bf16* __restrict__ Kh,
    float* __restrict__ P)
{
    const int z = blockIdx.z;
    const bf16* A = Qh + (size_t)z * SEQ * HIDDEN;
    const bf16* B = Kh + (size_t)z * SEQ * HIDDEN;
    float* C = P + (size_t)z * SEQ * SEQ;

    const int m0 = blockIdx.y * BM, n0 = blockIdx.x * BN;
    floatx4 acc[4][4] = {};
    mfma_nt(A, HIDDEN, B, HIDDEN, HIDDEN, m0, n0, acc);

    const int l = threadIdx.x & 63, w = threadIdx.x >> 6;
    const int rb = m0 + (w >> 1) * 64 + (l >> 4) * 4;
    const int cb = n0 + (w & 1) * 64 + (l & 15);
#pragma unroll
    for (int i = 0; i < 4; ++i)
#pragma unroll
        for (int j = 0; j < 4; ++j)
#pragma unroll
            for (int r = 0; r < 4; ++r)
                C[(size_t)(rb + i * 16 + r) * SEQ + cb + j * 16] =
                    acc[i][j][r] * INV_SQRT_HID;
}

// ---------------------------------------------------------------------------
// PROVEN structure + bf16 store (new): softmax-combine over 8 gated heads.
// reads Pf fp32, writes Pb bf16.
// ---------------------------------------------------------------------------
__global__ __launch_bounds__(256) void softmax_combine_kernel(
    const float* __restrict__ P, bf16* __restrict__ Pb,
    const float* __restrict__ strength, const float* __restrict__ gate)
{
    const int row = blockIdx.x;
    const int n = row >> 11;
    const float* prow = P + (size_t)row * SEQ;
    const int tid = threadIdx.x;
    const int wid = tid >> 6, lane = tid & 63;

    float4 v = ((const float4*)prow)[tid];

    float m = fmaxf(fmaxf(v.x, v.y), fmaxf(v.z, v.w));
#pragma unroll
    for (int off = 32; off > 0; off >>= 1) m = fmaxf(m, __shfl_down(m, off));
    __shared__ float redm[4];
    if (lane == 0) redm[wid] = m;
    __syncthreads();
    const float M = fmaxf(fmaxf(redm[0], redm[1]), fmaxf(redm[2], redm[3]));

    float sh[NH], gh[NH];
#pragma unroll
    for (int h = 0; h < NH; ++h) {
        sh[h] = fminf(fmaxf(strength[n * NH * NH + h * NH + h], 0.01f), 1.0f);
        gh[h] = gate[n * NH + h];
    }

    const float e[4] = { v.x - M, v.y - M, v.z - M, v.w - M };
    float E[4][NH];
    float zsum[NH];
#pragma unroll
    for (int h = 0; h < NH; ++h) zsum[h] = 0.f;
#pragma unroll
    for (int i = 0; i < 4; ++i)
#pragma unroll
        for (int h = 0; h < NH; ++h) {
            const float t = __expf(sh[h] * e[i]);
            E[i][h] = t; zsum[h] += t;
        }

#pragma unroll
    for (int h = 0; h < NH; ++h)
#pragma unroll
        for (int off = 32; off > 0; off >>= 1) zsum[h] += __shfl_down(zsum[h], off);
    __shared__ float redz[4][NH];
    if (lane == 0)
#pragma unroll
        for (int h = 0; h < NH; ++h) redz[wid][h] = zsum[h];
    __syncthreads();

    float wgt[NH];
#pragma unroll
    for (int h = 0; h < NH; ++h) {
        const float Z = redz[0][h] + redz[1][h] + redz[2][h] + redz[3][h];
        wgt[h] = gh[h] / Z;
    }

    bf16x4 o;
#pragma unroll
    for (int i = 0; i < 4; ++i) {
        float s = 0.f;
#pragma unroll
        for (int h = 0; h < NH; ++h) s += wgt[h] * E[i][h];
        o[i] = (bf16)s;
    }
    *(bf16x4*)&Pb[(size_t)row * SEQ + tid * 4] = o;
}

// ---------------------------------------------------------------------------
// NEW (= proven scores structure, K=1024): HS[z][s][d] = Pb[z] @ Vt[z]^T
// A = Pb[z] [s][t] lda=SEQ; B = Vt[z] [d][t] ldb=SEQ (NT). bf16 out.
// ---------------------------------------------------------------------------
__global__ __launch_bounds__(256) void pv_mfma_kernel(
    const bf16* __restrict__ Pb, const bf16* __restrict__ Vt,
    bf16* __restrict__ HS)
{
    const int z = blockIdx.z;
    const bf16* A = Pb + (size_t)z * SEQ * SEQ;
    const bf16* B = Vt + (size_t)z * HIDDEN * SEQ;
    bf16* C = HS + (size_t)z * SEQ * HIDDEN;

    const int m0 = blockIdx.y * BM, n0 = blockIdx.x * BN;
    floatx4 acc[4][4] = {};
    mfma_nt(A, SEQ, B, SEQ, SEQ, m0, n0, acc);

    const int l = threadIdx.x & 63, w = threadIdx.x >> 6;
    const int rb = m0 + (w >> 1) * 64 + (l >> 4) * 4;
    const int cb = n0 + (w & 1) * 64 + (l & 15);
#pragma unroll
    for (int i = 0; i < 4; ++i)
#pragma unroll
        for (int j = 0; j < 4; ++j)
#pragma unroll
            for (int r = 0; r < 4; ++r)
                C[(size_t)(rb + i * 16 + r) * HIDDEN + cb + j * 16] =
                    (bf16)acc[i][j][r];
}

// ---------------------------------------------------------------------------
// PROVEN: out projection via MFMA (n-loop).
// out[m][o] = MOD * ( sum_n HS[n][m] . WoT[n][o] + sum_n bo[n][o] )
// ---------------------------------------------------------------------------
__global__ __launch_bounds__(256) void out_mfma_kernel(
    const bf16* __restrict__ HS, const bf16* __restrict__ WoT,
    const float* __restrict__ bo, float* __restrict__ out)
{
    const int m0 = blockIdx.y * BM, n0 = blockIdx.x * BN;
    floatx4 acc[4][4] = {};
#pragma unroll
    for (int n = 0; n < NBLK; ++n)
        mfma_nt(HS + (size_t)n * (BATCH * SEQ) * HIDDEN, HIDDEN,
                WoT + (size_t)n * HIDDEN * DIM, HIDDEN,
                HIDDEN, m0, n0, acc);

    const int l = threadIdx.x & 63, w = threadIdx.x >> 6;
    const int rb = m0 + (w >> 1) * 64 + (l >> 4) * 4;
    const int cb = n0 + (w & 1) * 64 + (l & 15);
#pragma unroll
    for (int j = 0; j < 4; ++j) {
        const int col = cb + j * 16;
        float bs = 0.f;
#pragma unroll
        for (int n = 0; n < NBLK; ++n) bs += bo[n * DIM + col];
#pragma unroll
        for (int i = 0; i < 4; ++i)
#pragma unroll
            for (int r = 0; r < 4; ++r)
                out[(size_t)(rb + i * 16 + r) * DIM + col] =
                    (acc[i][j][r] + bs) * MODF;
    }
}

// ---------------------------------------------------------------------------
extern "C" void kernel_launch(void* const* d_in, const int* in_sizes, int n_in,
                              void* d_out, int out_size, void* d_ws, size_t ws_size,
                              hipStream_t stream) {
    const float* x        = (const float*)d_in[0];
    const float* Wq       = (const float*)d_in[1];
    const float* bq       = (const float*)d_in[2];
    const float* Wk       = (const float*)d_in[3];
    const float* bk       = (const float*)d_in[4];
    const float* Wv       = (const float*)d_in[5];
    const float* bv       = (const float*)d_in[6];
    const float* Wo       = (const float*)d_in[7];
    const float* bo       = (const float*)d_in[8];
    const float* strength = (const float*)d_in[9];
    const float* gate     = (const float*)d_in[10];
    float* out = (float*)d_out;

    // workspace (MiB offsets), total 74 MiB (<= proven 80):
    //   xb  [0,2) | WqT [2,4) | WkT [4,6) | WvT [6,8) | WoT [8,10)
    //   Qh  [10,18) | Kh [18,26) | Vm bf16 [26,34) | Vt bf16 [34,42)
    //   Pf fp32 [42,74)
    //   Pb bf16 (16 MiB) aliases [10,26)  (Qh/Kh dead after scores)
    //   HS bf16 (8 MiB)  aliases [26,34)  (Vm dead after transpose_v)
    char* ws = (char*)d_ws;
    bf16*  xb  = (bf16*)(ws);
    bf16*  WqT = (bf16*)(ws + (2u  << 20));
    bf16*  WkT = (bf16*)(ws + (4u  << 20));
    bf16*  WvT = (bf16*)(ws + (6u  << 20));
    bf16*  WoT = (bf16*)(ws + (8u  << 20));
    bf16*  Qh  = (bf16*)(ws + (10u << 20));
    bf16*  Kh  = (bf16*)(ws + (18u << 20));
    bf16*  Vm  = (bf16*)(ws + (26u << 20));
    bf16*  Vt  = (bf16*)(ws + (34u << 20));
    float* Pf  = (float*)(ws + (42u << 20));
    bf16*  Pb  = (bf16*)(ws + (10u << 20));  // alias over dead Qh/Kh
    bf16*  HS  = (bf16*)(ws + (26u << 20));  // alias over dead Vm

    // prep
    xconv_kernel<<<dim3((BATCH * SEQ * DIM) / 1024), 256, 0, stream>>>(x, xb);
    transpose_w_kernel<<<dim3(16, 16, 16), 256, 0, stream>>>(
        Wq, Wk, Wv, Wo, WqT, WkT, WvT, WoT);

    // 1) QKV projections via MFMA: grid (4, 16, 12); all outputs bf16 [m][h]
    proj_mfma_kernel<<<dim3(HIDDEN / BN, (BATCH * SEQ) / BM, 3 * NBLK), 256, 0, stream>>>(
        xb, WqT, WkT, WvT, bq, bk, bv, Qh, Kh, Vm);

    // 1b) V transpose per z-slice: Vt[z][d][t] = Vm[z][t][d]; grid (16, 32, 8)
    transpose_v_kernel<<<dim3(HIDDEN / 32, SEQ / 32, NBLK * BATCH), 256, 0, stream>>>(
        Vm, Vt);

    // 2) scores via MFMA: grid (8, 8, 8)
    scores_mfma_kernel<<<dim3(SEQ / BN, SEQ / BM, NBLK * BATCH), 256, 0, stream>>>(
        Qh, Kh, Pf);

    // 3) softmax-combine: fp32 in, bf16 out
    softmax_combine_kernel<<<dim3(NBLK * BATCH * SEQ), 256, 0, stream>>>(
        Pf, Pb, strength, gate);

    // 4) head_sum via MFMA: grid (4, 8, 8)
    pv_mfma_kernel<<<dim3(HIDDEN / BN, SEQ / BM, NBLK * BATCH), 256, 0, stream>>>(
        Pb, Vt, HS);

    // 5) output projection via MFMA: grid (4, 16)
    out_mfma_kernel<<<dim3(DIM / BN, (BATCH * SEQ) / BM, 1), 256, 0, stream>>>(
        HS, WoT, bo, out);
}

// Round 8
// 204.313 us; speedup vs baseline: 3.1854x; 1.1314x over previous
//
#include <hip/hip_runtime.h>
#include <math.h>

// Problem constants (from reference)
#define NBLK   4      // NB: blocks
#define NH     8      // H: heads
#define BATCH  2      // B
#define SEQ    1024   // S
#define DIM    512    // D
#define HIDDEN 512    // HID
#define MODF   1.55f  // MOD
#define INV_SQRT_HID 0.04419417382415922f  // 1/sqrt(512)

typedef __bf16 bf16;
typedef __bf16 bf16x4 __attribute__((ext_vector_type(4)));
typedef __bf16 bf16x8 __attribute__((ext_vector_type(8)));
typedef float  floatx4 __attribute__((ext_vector_type(4)));

// ---------------- bf16 MFMA NT core, m97 DMA staging ----------------
// 128x128 C-tile, BK=32, 4 waves. LDS [row][32] UNPADDED: global_load_lds
// lands at wave-uniform base + lane*16 (m104), so LDS must be contiguous in
// lane order: lane l -> byte s*1024 + l*16 = row s*16+l/4, k (l&3)*8. The
// global address below is exactly that element. Fragment reads and MFMA
// are byte-identical to the R4-proven core.
constexpr int BM = 128, BN = 128, BK = 32;

__device__ __forceinline__ void load16_lds(const bf16* g, bf16* l) {
    __builtin_amdgcn_global_load_lds(
        (__attribute__((address_space(1))) void*)g,
        (__attribute__((address_space(3))) void*)l, 16, 0, 0);
}

__device__ __forceinline__ void mfma_nt(
    const bf16* __restrict__ A, int lda,
    const bf16* __restrict__ B, int ldb,
    int K, int m0, int n0, floatx4 (&acc)[4][4])
{
    __shared__ __align__(16) bf16 As[BM * BK];   // 8 KiB
    __shared__ __align__(16) bf16 Bs[BN * BK];   // 8 KiB

    const int tid = threadIdx.x;
    const int l   = tid & 63;
    const int w   = tid >> 6;
    const int wr  = (w >> 1) * 64;
    const int wc  = (w & 1) * 64;

    // staging: wave w fills 1-KiB segments {2w, 2w+1}; lane l sources
    // row seg*16 + l/4, k-chunk (l&3)*8 (16 B) — matches DMA lane layout.
    const int s0 = 2 * w, s1 = s0 + 1;
    const int r0 = s0 * 16 + (l >> 2);
    const int r1 = s1 * 16 + (l >> 2);
    const int kc = (l & 3) * 8;

    const int fr = l & 15;
    const int fk = (l >> 4) * 8;

    const bf16* Ab = A + (size_t)m0 * lda;
    const bf16* Bb = B + (size_t)n0 * ldb;

    for (int k0 = 0; k0 < K; k0 += BK) {
        __syncthreads();   // WAR: prior ds_reads done before DMA overwrites
        load16_lds(Ab + (size_t)r0 * lda + k0 + kc, As + s0 * 512);
        load16_lds(Ab + (size_t)r1 * lda + k0 + kc, As + s1 * 512);
        load16_lds(Bb + (size_t)r0 * ldb + k0 + kc, Bs + s0 * 512);
        load16_lds(Bb + (size_t)r1 * ldb + k0 + kc, Bs + s1 * 512);
        __syncthreads();   // drains vmcnt before s_barrier -> LDS valid

        bf16x8 af[4], bg[4];
#pragma unroll
        for (int i = 0; i < 4; ++i)
            af[i] = *(const bf16x8*)&As[(wr + i * 16 + fr) * BK + fk];
#pragma unroll
        for (int j = 0; j < 4; ++j)
            bg[j] = *(const bf16x8*)&Bs[(wc + j * 16 + fr) * BK + fk];
#pragma unroll
        for (int i = 0; i < 4; ++i)
#pragma unroll
            for (int j = 0; j < 4; ++j)
                acc[i][j] = __builtin_amdgcn_mfma_f32_16x16x32_bf16(
                    af[i], bg[j], acc[i][j], 0, 0, 0);
    }
}

// ---------------------------------------------------------------------------
// PROVEN Prep 1: x fp32 [2048][512] -> xb bf16 same layout
// ---------------------------------------------------------------------------
__global__ __launch_bounds__(256) void xconv_kernel(
    const float* __restrict__ x, bf16* __restrict__ xb)
{
    const int t = blockIdx.x * 256 + threadIdx.x;
    const float4 v = ((const float4*)x)[t];
    bf16x4 o = { (bf16)v.x, (bf16)v.y, (bf16)v.z, (bf16)v.w };
    *(bf16x4*)&xb[(size_t)t * 4] = o;
}

// ---------------------------------------------------------------------------
// PROVEN Prep 2: transpose + bf16-cast weight slices. dst[h][d] = src[d][h].
// ---------------------------------------------------------------------------
__global__ __launch_bounds__(256) void transpose_w_kernel(
    const float* __restrict__ Wq, const float* __restrict__ Wk,
    const float* __restrict__ Wv, const float* __restrict__ Wo,
    bf16* __restrict__ WqT, bf16* __restrict__ WkT,
    bf16* __restrict__ WvT, bf16* __restrict__ WoT)
{
    __shared__ float tile[32][33];
    const int z = blockIdx.z;
    const int mat = z >> 2, n = z & 3;
    const float* src; bf16* dst;
    if (mat == 0)      { src = Wq; dst = WqT; }
    else if (mat == 1) { src = Wk; dst = WkT; }
    else if (mat == 2) { src = Wv; dst = WvT; }
    else               { src = Wo; dst = WoT; }
    src += (size_t)n * 512 * 512;
    dst += (size_t)n * 512 * 512;

    const int tx = threadIdx.x & 31, ty = threadIdx.x >> 5;   // 32 x 8
    const int x0 = blockIdx.x * 32, y0 = blockIdx.y * 32;
#pragma unroll
    for (int r = 0; r < 4; ++r)
        tile[ty + r * 8][tx] = src[(size_t)(y0 + ty + r * 8) * 512 + x0 + tx];
    __syncthreads();
#pragma unroll
    for (int r = 0; r < 4; ++r)
        dst[(size_t)(x0 + ty + r * 8) * 512 + y0 + tx] = (bf16)tile[tx][ty + r * 8];
}

// ---------------------------------------------------------------------------
// PROVEN: bf16 transpose of V per z-slice. Vt[z][d][t] = Vm[z][t][d].
// ---------------------------------------------------------------------------
__global__ __launch_bounds__(256) void transpose_v_kernel(
    const bf16* __restrict__ Vm, bf16* __restrict__ Vt)
{
    __shared__ float tile[32][33];
    const int z = blockIdx.z;
    const bf16* src = Vm + (size_t)z * SEQ * HIDDEN;
    bf16*       dst = Vt + (size_t)z * HIDDEN * SEQ;

    const int tx = threadIdx.x & 31, ty = threadIdx.x >> 5;
    const int x0 = blockIdx.x * 32;   // over HIDDEN
    const int y0 = blockIdx.y * 32;   // over SEQ
#pragma unroll
    for (int r = 0; r < 4; ++r)
        tile[ty + r * 8][tx] = (float)src[(size_t)(y0 + ty + r * 8) * HIDDEN + x0 + tx];
    __syncthreads();
#pragma unroll
    for (int r = 0; r < 4; ++r)
        dst[(size_t)(x0 + ty + r * 8) * SEQ + y0 + tx] = (bf16)tile[tx][ty + r * 8];
}

// ---------------------------------------------------------------------------
// PROVEN: QKV projections via MFMA.  z = which*4 + n.  bf16 out [m][h].
// ---------------------------------------------------------------------------
__global__ __launch_bounds__(256) void proj_mfma_kernel(
    const bf16* __restrict__ xb,
    const bf16* __restrict__ WqT, const bf16* __restrict__ WkT,
    const bf16* __restrict__ WvT,
    const float* __restrict__ bq, const float* __restrict__ bk,
    const float* __restrict__ bv,
    bf16* __restrict__ Qh, bf16* __restrict__ Kh, bf16* __restrict__ Vm)
{
    const int z = blockIdx.z;
    const int n = z & 3, which = z >> 2;
    const bf16* WT; const float* bias; bf16* Cb;
    if (which == 0)      { WT = WqT; bias = bq; Cb = Qh; }
    else if (which == 1) { WT = WkT; bias = bk; Cb = Kh; }
    else                 { WT = WvT; bias = bv; Cb = Vm; }
    WT   += (size_t)n * DIM * HIDDEN;
    bias += (size_t)n * HIDDEN;
    bf16* C = Cb + (size_t)n * (BATCH * SEQ) * HIDDEN;

    const int m0 = blockIdx.y * BM, n0 = blockIdx.x * BN;
    floatx4 acc[4][4] = {};
    mfma_nt(xb, DIM, WT, DIM, DIM, m0, n0, acc);

    const int l = threadIdx.x & 63, w = threadIdx.x >> 6;
    const int rb = m0 + (w >> 1) * 64 + (l >> 4) * 4;
    const int cb = n0 + (w & 1) * 64 + (l & 15);
#pragma unroll
    for (int j = 0; j < 4; ++j) {
        const int col = cb + j * 16;
        const float bc = bias[col];
#pragma unroll
        for (int i = 0; i < 4; ++i)
#pragma unroll
            for (int r = 0; r < 4; ++r)
                C[(size_t)(rb + i * 16 + r) * HIDDEN + col] = (bf16)(acc[i][j][r] + bc);
    }
}

// ---------------------------------------------------------------------------
// PROVEN: scores via MFMA: P[z][s][t] = (Q[z][s].K[z][t]) / sqrt(HID)
// ---------------------------------------------------------------------------
__global__ __launch_bounds__(256) void scores_mfma_kernel(
    const bf16* __restrict__ Qh, const bf16* __restrict__ Kh,
    float* __restrict__ P)
{
    const int z = blockIdx.z;
    const bf16* A = Qh + (size_t)z * SEQ * HIDDEN;
    const bf16* B = Kh + (size_t)z * SEQ * HIDDEN;
    float* C = P + (size_t)z * SEQ * SEQ;

    const int m0 = blockIdx.y * BM, n0 = blockIdx.x * BN;
    floatx4 acc[4][4] = {};
    mfma_nt(A, HIDDEN, B, HIDDEN, HIDDEN, m0, n0, acc);

    const int l = threadIdx.x & 63, w = threadIdx.x >> 6;
    const int rb = m0 + (w >> 1) * 64 + (l >> 4) * 4;
    const int cb = n0 + (w & 1) * 64 + (l & 15);
#pragma unroll
    for (int i = 0; i < 4; ++i)
#pragma unroll
        for (int j = 0; j < 4; ++j)
#pragma unroll
            for (int r = 0; r < 4; ++r)
                C[(size_t)(rb + i * 16 + r) * SEQ + cb + j * 16] =
                    acc[i][j][r] * INV_SQRT_HID;
}

// ---------------------------------------------------------------------------
// PROVEN: softmax-combine over 8 gated heads. fp32 in, bf16 out.
// ---------------------------------------------------------------------------
__global__ __launch_bounds__(256) void softmax_combine_kernel(
    const float* __restrict__ P, bf16* __restrict__ Pb,
    const float* __restrict__ strength, const float* __restrict__ gate)
{
    const int row = blockIdx.x;
    const int n = row >> 11;
    const float* prow = P + (size_t)row * SEQ;
    const int tid = threadIdx.x;
    const int wid = tid >> 6, lane = tid & 63;

    float4 v = ((const float4*)prow)[tid];

    float m = fmaxf(fmaxf(v.x, v.y), fmaxf(v.z, v.w));
#pragma unroll
    for (int off = 32; off > 0; off >>= 1) m = fmaxf(m, __shfl_down(m, off));
    __shared__ float redm[4];
    if (lane == 0) redm[wid] = m;
    __syncthreads();
    const float M = fmaxf(fmaxf(redm[0], redm[1]), fmaxf(redm[2], redm[3]));

    float sh[NH], gh[NH];
#pragma unroll
    for (int h = 0; h < NH; ++h) {
        sh[h] = fminf(fmaxf(strength[n * NH * NH + h * NH + h], 0.01f), 1.0f);
        gh[h] = gate[n * NH + h];
    }

    const float e[4] = { v.x - M, v.y - M, v.z - M, v.w - M };
    float E[4][NH];
    float zsum[NH];
#pragma unroll
    for (int h = 0; h < NH; ++h) zsum[h] = 0.f;
#pragma unroll
    for (int i = 0; i < 4; ++i)
#pragma unroll
        for (int h = 0; h < NH; ++h) {
            const float t = __expf(sh[h] * e[i]);
            E[i][h] = t; zsum[h] += t;
        }

#pragma unroll
    for (int h = 0; h < NH; ++h)
#pragma unroll
        for (int off = 32; off > 0; off >>= 1) zsum[h] += __shfl_down(zsum[h], off);
    __shared__ float redz[4][NH];
    if (lane == 0)
#pragma unroll
        for (int h = 0; h < NH; ++h) redz[wid][h] = zsum[h];
    __syncthreads();

    float wgt[NH];
#pragma unroll
    for (int h = 0; h < NH; ++h) {
        const float Z = redz[0][h] + redz[1][h] + redz[2][h] + redz[3][h];
        wgt[h] = gh[h] / Z;
    }

    bf16x4 o;
#pragma unroll
    for (int i = 0; i < 4; ++i) {
        float s = 0.f;
#pragma unroll
        for (int h = 0; h < NH; ++h) s += wgt[h] * E[i][h];
        o[i] = (bf16)s;
    }
    *(bf16x4*)&Pb[(size_t)row * SEQ + tid * 4] = o;
}

// ---------------------------------------------------------------------------
// PROVEN: HS[z][s][d] = Pb[z] @ Vt[z]^T  (NT, K=SEQ). bf16 out.
// ---------------------------------------------------------------------------
__global__ __launch_bounds__(256) void pv_mfma_kernel(
    const bf16* __restrict__ Pb, const bf16* __restrict__ Vt,
    bf16* __restrict__ HS)
{
    const int z = blockIdx.z;
    const bf16* A = Pb + (size_t)z * SEQ * SEQ;
    const bf16* B = Vt + (size_t)z * HIDDEN * SEQ;
    bf16* C = HS + (size_t)z * SEQ * HIDDEN;

    const int m0 = blockIdx.y * BM, n0 = blockIdx.x * BN;
    floatx4 acc[4][4] = {};
    mfma_nt(A, SEQ, B, SEQ, SEQ, m0, n0, acc);

    const int l = threadIdx.x & 63, w = threadIdx.x >> 6;
    const int rb = m0 + (w >> 1) * 64 + (l >> 4) * 4;
    const int cb = n0 + (w & 1) * 64 + (l & 15);
#pragma unroll
    for (int i = 0; i < 4; ++i)
#pragma unroll
        for (int j = 0; j < 4; ++j)
#pragma unroll
            for (int r = 0; r < 4; ++r)
                C[(size_t)(rb + i * 16 + r) * HIDDEN + cb + j * 16] =
                    (bf16)acc[i][j][r];
}

// ---------------------------------------------------------------------------
// NEW (occupancy fix): out projection partials, n in blockIdx.z (256 blocks).
// Opart[n][m][o] = HS[n][m] . WoT[n][o]   (fp32, exact adds in reduce)
// Store = proven scores epilogue (fp32, no scale).
// ---------------------------------------------------------------------------
__global__ __launch_bounds__(256) void out_partial_kernel(
    const bf16* __restrict__ HS, const bf16* __restrict__ WoT,
    float* __restrict__ Opart)
{
    const int n = blockIdx.z;
    const bf16* A = HS + (size_t)n * (BATCH * SEQ) * HIDDEN;
    const bf16* B = WoT + (size_t)n * HIDDEN * DIM;
    float* C = Opart + (size_t)n * (BATCH * SEQ) * DIM;

    const int m0 = blockIdx.y * BM, n0 = blockIdx.x * BN;
    floatx4 acc[4][4] = {};
    mfma_nt(A, HIDDEN, B, HIDDEN, HIDDEN, m0, n0, acc);

    const int l = threadIdx.x & 63, w = threadIdx.x >> 6;
    const int rb = m0 + (w >> 1) * 64 + (l >> 4) * 4;
    const int cb = n0 + (w & 1) * 64 + (l & 15);
#pragma unroll
    for (int i = 0; i < 4; ++i)
#pragma unroll
        for (int j = 0; j < 4; ++j)
#pragma unroll
            for (int r = 0; r < 4; ++r)
                C[(size_t)(rb + i * 16 + r) * DIM + cb + j * 16] = acc[i][j][r];
}

// ---------------------------------------------------------------------------
// NEW: reduce 4 partials + bias + MOD. out[m][o] = MOD*(sum_n part + sum_n bo)
// one float4 per thread over 2048*512 elements.
// ---------------------------------------------------------------------------
__global__ __launch_bounds__(256) void out_reduce_kernel(
    const float* __restrict__ Opart, const float* __restrict__ bo,
    float* __restrict__ out)
{
    const size_t t = (size_t)blockIdx.x * 256 + threadIdx.x;   // float4 index
    const int c = (int)((t * 4) & (DIM - 1));                  // col of .x
    const size_t stride4 = (size_t)(BATCH * SEQ) * DIM / 4;

    float4 s = ((const float4*)Opart)[t];
#pragma unroll
    for (int n = 1; n < NBLK; ++n) {
        const float4 p = ((const float4*)Opart)[t + n * stride4];
        s.x += p.x; s.y += p.y; s.z += p.z; s.w += p.w;
    }
    float4 bs = make_float4(0.f, 0.f, 0.f, 0.f);
#pragma unroll
    for (int n = 0; n < NBLK; ++n) {
        const float4 b = *(const float4*)(bo + n * DIM + c);
        bs.x += b.x; bs.y += b.y; bs.z += b.z; bs.w += b.w;
    }
    ((float4*)out)[t] = make_float4((s.x + bs.x) * MODF, (s.y + bs.y) * MODF,
                                    (s.z + bs.z) * MODF, (s.w + bs.w) * MODF);
}

// ---------------------------------------------------------------------------
extern "C" void kernel_launch(void* const* d_in, const int* in_sizes, int n_in,
                              void* d_out, int out_size, void* d_ws, size_t ws_size,
                              hipStream_t stream) {
    const float* x        = (const float*)d_in[0];
    const float* Wq       = (const float*)d_in[1];
    const float* bq       = (const float*)d_in[2];
    const float* Wk       = (const float*)d_in[3];
    const float* bk       = (const float*)d_in[4];
    const float* Wv       = (const float*)d_in[5];
    const float* bv       = (const float*)d_in[6];
    const float* Wo       = (const float*)d_in[7];
    const float* bo       = (const float*)d_in[8];
    const float* strength = (const float*)d_in[9];
    const float* gate     = (const float*)d_in[10];
    float* out = (float*)d_out;

    // workspace (MiB offsets), total 74 MiB:
    //   xb  [0,2) | WqT [2,4) | WkT [4,6) | WvT [6,8) | WoT [8,10)
    //   Qh  [10,18) | Kh [18,26) | Vm bf16 [26,34) | Vt bf16 [34,42)
    //   Pf fp32 [42,74)
    //   Pb bf16 (16 MiB) aliases [10,26)  (Qh/Kh dead after scores)
    //   HS bf16 (8 MiB)  aliases [26,34)  (Vm dead after transpose_v)
    //   Opart fp32 (16 MiB) aliases [42,58) (Pf dead after softmax)
    char* ws = (char*)d_ws;
    bf16*  xb    = (bf16*)(ws);
    bf16*  WqT   = (bf16*)(ws + (2u  << 20));
    bf16*  WkT   = (bf16*)(ws + (4u  << 20));
    bf16*  WvT   = (bf16*)(ws + (6u  << 20));
    bf16*  WoT   = (bf16*)(ws + (8u  << 20));
    bf16*  Qh    = (bf16*)(ws + (10u << 20));
    bf16*  Kh    = (bf16*)(ws + (18u << 20));
    bf16*  Vm    = (bf16*)(ws + (26u << 20));
    bf16*  Vt    = (bf16*)(ws + (34u << 20));
    float* Pf    = (float*)(ws + (42u << 20));
    bf16*  Pb    = (bf16*)(ws + (10u << 20));  // alias over dead Qh/Kh
    bf16*  HS    = (bf16*)(ws + (26u << 20));  // alias over dead Vm
    float* Opart = (float*)(ws + (42u << 20)); // alias over dead Pf

    // prep
    xconv_kernel<<<dim3((BATCH * SEQ * DIM) / 1024), 256, 0, stream>>>(x, xb);
    transpose_w_kernel<<<dim3(16, 16, 16), 256, 0, stream>>>(
        Wq, Wk, Wv, Wo, WqT, WkT, WvT, WoT);

    // 1) QKV projections via MFMA: grid (4, 16, 12)
    proj_mfma_kernel<<<dim3(HIDDEN / BN, (BATCH * SEQ) / BM, 3 * NBLK), 256, 0, stream>>>(
        xb, WqT, WkT, WvT, bq, bk, bv, Qh, Kh, Vm);

    // 1b) V transpose: grid (16, 32, 8)
    transpose_v_kernel<<<dim3(HIDDEN / 32, SEQ / 32, NBLK * BATCH), 256, 0, stream>>>(
        Vm, Vt);

    // 2) scores via MFMA: grid (8, 8, 8)
    scores_mfma_kernel<<<dim3(SEQ / BN, SEQ / BM, NBLK * BATCH), 256, 0, stream>>>(
        Qh, Kh, Pf);

    // 3) softmax-combine: fp32 in, bf16 out
    softmax_combine_kernel<<<dim3(NBLK * BATCH * SEQ), 256, 0, stream>>>(
        Pf, Pb, strength, gate);

    // 4) head_sum via MFMA: grid (4, 8, 8)
    pv_mfma_kernel<<<dim3(HIDDEN / BN, SEQ / BM, NBLK * BATCH), 256, 0, stream>>>(
        Pb, Vt, HS);

    // 5) out projection partials: grid (4, 16, 4) = 256 blocks
    out_partial_kernel<<<dim3(DIM / BN, (BATCH * SEQ) / BM, NBLK), 256, 0, stream>>>(
        HS, WoT, Opart);

    // 5b) reduce + bias + MOD: 2048*512/4 threads
    out_reduce_kernel<<<dim3((BATCH * SEQ) * DIM / 4 / 256), 256, 0, stream>>>(
        Opart, bo, out);
}

// Round 9
// 194.216 us; speedup vs baseline: 3.3510x; 1.0520x over previous
//
#include <hip/hip_runtime.h>
#include <math.h>

// Problem constants (from reference)
#define NBLK   4      // NB: blocks
#define NH     8      // H: heads
#define BATCH  2      // B
#define SEQ    1024   // S
#define DIM    512    // D
#define HIDDEN 512    // HID
#define MODF   1.55f  // MOD
#define INV_SQRT_HID 0.04419417382415922f  // 1/sqrt(512)

typedef __bf16 bf16;
typedef __bf16 bf16x4 __attribute__((ext_vector_type(4)));
typedef __bf16 bf16x8 __attribute__((ext_vector_type(8)));
typedef float  floatx4 __attribute__((ext_vector_type(4)));

// ---------------- bf16 MFMA NT core, DMA staging + double buffer ----------
// 128x128 C-tile, BK=32, 4 waves. Two LDS buffer pairs (32 KiB total).
// Per K-step: ONE barrier; next tile's DMA is issued before computing the
// current tile, so the vmcnt drain at the next barrier waits only
// (DMA latency - compute time). Accumulation order identical to R8.
constexpr int BM = 128, BN = 128, BK = 32;

__device__ __forceinline__ void load16_lds(const bf16* g, bf16* l) {
    __builtin_amdgcn_global_load_lds(
        (__attribute__((address_space(1))) void*)g,
        (__attribute__((address_space(3))) void*)l, 16, 0, 0);
}

// stage one 128x32 A-tile + 128x32 B-tile into (As,Bs).
// wave w fills 1-KiB segments {2w,2w+1}; lane l -> row seg*16+l/4, k (l&3)*8.
__device__ __forceinline__ void stage32(
    const bf16* __restrict__ Ab, int lda,
    const bf16* __restrict__ Bb, int ldb, int k0,
    bf16* As, bf16* Bs, int w, int l)
{
    const int s0 = 2 * w, s1 = s0 + 1;
    const int r0 = s0 * 16 + (l >> 2);
    const int r1 = s1 * 16 + (l >> 2);
    const int kc = (l & 3) * 8;
    load16_lds(Ab + (size_t)r0 * lda + k0 + kc, As + s0 * 512);
    load16_lds(Ab + (size_t)r1 * lda + k0 + kc, As + s1 * 512);
    load16_lds(Bb + (size_t)r0 * ldb + k0 + kc, Bs + s0 * 512);
    load16_lds(Bb + (size_t)r1 * ldb + k0 + kc, Bs + s1 * 512);
}

// one K=32 compute step from (As,Bs): 16 MFMA per wave.
__device__ __forceinline__ void comp32(
    const bf16* As, const bf16* Bs,
    int wr, int wc, int fr, int fk, floatx4 (&acc)[4][4])
{
    bf16x8 af[4], bg[4];
#pragma unroll
    for (int i = 0; i < 4; ++i)
        af[i] = *(const bf16x8*)&As[(wr + i * 16 + fr) * BK + fk];
#pragma unroll
    for (int j = 0; j < 4; ++j)
        bg[j] = *(const bf16x8*)&Bs[(wc + j * 16 + fr) * BK + fk];
#pragma unroll
    for (int i = 0; i < 4; ++i)
#pragma unroll
        for (int j = 0; j < 4; ++j)
            acc[i][j] = __builtin_amdgcn_mfma_f32_16x16x32_bf16(
                af[i], bg[j], acc[i][j], 0, 0, 0);
}

__device__ __forceinline__ void mfma_nt(
    const bf16* __restrict__ A, int lda,
    const bf16* __restrict__ B, int ldb,
    int K, int m0, int n0, floatx4 (&acc)[4][4])
{
    __shared__ __align__(16) bf16 As0[BM * BK];   // 8 KiB each
    __shared__ __align__(16) bf16 Bs0[BN * BK];
    __shared__ __align__(16) bf16 As1[BM * BK];
    __shared__ __align__(16) bf16 Bs1[BN * BK];

    const int tid = threadIdx.x;
    const int l   = tid & 63;
    const int w   = tid >> 6;
    const int wr  = (w >> 1) * 64;
    const int wc  = (w & 1) * 64;
    const int fr  = l & 15;
    const int fk  = (l >> 4) * 8;

    const bf16* Ab = A + (size_t)m0 * lda;
    const bf16* Bb = B + (size_t)n0 * ldb;

    const int nIter = K / BK;       // always even here (16 or 32)
    stage32(Ab, lda, Bb, ldb, 0, As0, Bs0, w, l);
    for (int k = 0; k < nIter; k += 2) {
        __syncthreads();   // drains DMA for buf0 (issued one step ago) + WAR buf1
        if (k + 1 < nIter)
            stage32(Ab, lda, Bb, ldb, (k + 1) * BK, As1, Bs1, w, l);
        comp32(As0, Bs0, wr, wc, fr, fk, acc);
        __syncthreads();   // drains DMA for buf1 + WAR buf0
        if (k + 2 < nIter)
            stage32(Ab, lda, Bb, ldb, (k + 2) * BK, As0, Bs0, w, l);
        comp32(As1, Bs1, wr, wc, fr, fk, acc);
    }
}

// ---------------------------------------------------------------------------
// PROVEN Prep 1: x fp32 [2048][512] -> xb bf16 same layout
// ---------------------------------------------------------------------------
__global__ __launch_bounds__(256) void xconv_kernel(
    const float* __restrict__ x, bf16* __restrict__ xb)
{
    const int t = blockIdx.x * 256 + threadIdx.x;
    const float4 v = ((const float4*)x)[t];
    bf16x4 o = { (bf16)v.x, (bf16)v.y, (bf16)v.z, (bf16)v.w };
    *(bf16x4*)&xb[(size_t)t * 4] = o;
}

// ---------------------------------------------------------------------------
// PROVEN Prep 2: transpose + bf16-cast weight slices. dst[h][d] = src[d][h].
// ---------------------------------------------------------------------------
__global__ __launch_bounds__(256) void transpose_w_kernel(
    const float* __restrict__ Wq, const float* __restrict__ Wk,
    const float* __restrict__ Wv, const float* __restrict__ Wo,
    bf16* __restrict__ WqT, bf16* __restrict__ WkT,
    bf16* __restrict__ WvT, bf16* __restrict__ WoT)
{
    __shared__ float tile[32][33];
    const int z = blockIdx.z;
    const int mat = z >> 2, n = z & 3;
    const float* src; bf16* dst;
    if (mat == 0)      { src = Wq; dst = WqT; }
    else if (mat == 1) { src = Wk; dst = WkT; }
    else if (mat == 2) { src = Wv; dst = WvT; }
    else               { src = Wo; dst = WoT; }
    src += (size_t)n * 512 * 512;
    dst += (size_t)n * 512 * 512;

    const int tx = threadIdx.x & 31, ty = threadIdx.x >> 5;   // 32 x 8
    const int x0 = blockIdx.x * 32, y0 = blockIdx.y * 32;
#pragma unroll
    for (int r = 0; r < 4; ++r)
        tile[ty + r * 8][tx] = src[(size_t)(y0 + ty + r * 8) * 512 + x0 + tx];
    __syncthreads();
#pragma unroll
    for (int r = 0; r < 4; ++r)
        dst[(size_t)(x0 + ty + r * 8) * 512 + y0 + tx] = (bf16)tile[tx][ty + r * 8];
}

// ---------------------------------------------------------------------------
// QKV projections via MFMA.  z = which*4 + n.
// which 0 -> Qh bf16 [m][h], 1 -> Kh bf16 [m][h],
// which 2 -> Vt bf16 TRANSPOSED: Vt[(n*B+b)][d][t] (fuses old transpose_v;
//            per-lane bf16x4 along t — 4 consecutive rows r are contiguous).
// ---------------------------------------------------------------------------
__global__ __launch_bounds__(256) void proj_mfma_kernel(
    const bf16* __restrict__ xb,
    const bf16* __restrict__ WqT, const bf16* __restrict__ WkT,
    const bf16* __restrict__ WvT,
    const float* __restrict__ bq, const float* __restrict__ bk,
    const float* __restrict__ bv,
    bf16* __restrict__ Qh, bf16* __restrict__ Kh, bf16* __restrict__ Vt)
{
    const int z = blockIdx.z;
    const int n = z & 3, which = z >> 2;
    const bf16* WT; const float* bias;
    if (which == 0)      { WT = WqT; bias = bq; }
    else if (which == 1) { WT = WkT; bias = bk; }
    else                 { WT = WvT; bias = bv; }
    WT   += (size_t)n * DIM * HIDDEN;
    bias += (size_t)n * HIDDEN;

    const int m0 = blockIdx.y * BM, n0 = blockIdx.x * BN;
    floatx4 acc[4][4] = {};
    mfma_nt(xb, DIM, WT, DIM, DIM, m0, n0, acc);

    const int l = threadIdx.x & 63, w = threadIdx.x >> 6;
    const int rb = m0 + (w >> 1) * 64 + (l >> 4) * 4;
    const int cb = n0 + (w & 1) * 64 + (l & 15);

    if (which != 2) {
        bf16* C = (which ? Kh : Qh) + (size_t)n * (BATCH * SEQ) * HIDDEN;
#pragma unroll
        for (int j = 0; j < 4; ++j) {
            const int col = cb + j * 16;
            const float bc = bias[col];
#pragma unroll
            for (int i = 0; i < 4; ++i)
#pragma unroll
                for (int r = 0; r < 4; ++r)
                    C[(size_t)(rb + i * 16 + r) * HIDDEN + col] = (bf16)(acc[i][j][r] + bc);
        }
    } else {
        // transposed store: row m = b*SEQ + s -> Vt[z=n*B+b][d=col][t=s]
        const int b = m0 >> 10;                       // BM=128 tile never crosses
        bf16* Cv = Vt + (size_t)(n * BATCH + b) * HIDDEN * SEQ;
        const int tb = rb & (SEQ - 1);                // s-offset of quad row
#pragma unroll
        for (int j = 0; j < 4; ++j) {
            const int col = cb + j * 16;
            const float bc = bias[col];
#pragma unroll
            for (int i = 0; i < 4; ++i) {
                bf16x4 o = { (bf16)(acc[i][j][0] + bc), (bf16)(acc[i][j][1] + bc),
                             (bf16)(acc[i][j][2] + bc), (bf16)(acc[i][j][3] + bc) };
                *(bf16x4*)&Cv[(size_t)col * SEQ + tb + i * 16] = o;
            }
        }
    }
}

// ---------------------------------------------------------------------------
// PROVEN: scores via MFMA: P[z][s][t] = (Q[z][s].K[z][t]) / sqrt(HID)
// ---------------------------------------------------------------------------
__global__ __launch_bounds__(256) void scores_mfma_kernel(
    const bf16* __restrict__ Qh, const bf16* __restrict__ Kh,
    float* __restrict__ P)
{
    const int z = blockIdx.z;
    const bf16* A = Qh + (size_t)z * SEQ * HIDDEN;
    const bf16* B = Kh + (size_t)z * SEQ * HIDDEN;
    float* C = P + (size_t)z * SEQ * SEQ;

    const int m0 = blockIdx.y * BM, n0 = blockIdx.x * BN;
    floatx4 acc[4][4] = {};
    mfma_nt(A, HIDDEN, B, HIDDEN, HIDDEN, m0, n0, acc);

    const int l = threadIdx.x & 63, w = threadIdx.x >> 6;
    const int rb = m0 + (w >> 1) * 64 + (l >> 4) * 4;
    const int cb = n0 + (w & 1) * 64 + (l & 15);
#pragma unroll
    for (int i = 0; i < 4; ++i)
#pragma unroll
        for (int j = 0; j < 4; ++j)
#pragma unroll
            for (int r = 0; r < 4; ++r)
                C[(size_t)(rb + i * 16 + r) * SEQ + cb + j * 16] =
                    acc[i][j][r] * INV_SQRT_HID;
}

// ---------------------------------------------------------------------------
// PROVEN: softmax-combine over 8 gated heads. fp32 in, bf16 out.
// ---------------------------------------------------------------------------
__global__ __launch_bounds__(256) void softmax_combine_kernel(
    const float* __restrict__ P, bf16* __restrict__ Pb,
    const float* __restrict__ strength, const float* __restrict__ gate)
{
    const int row = blockIdx.x;
    const int n = row >> 11;
    const float* prow = P + (size_t)row * SEQ;
    const int tid = threadIdx.x;
    const int wid = tid >> 6, lane = tid & 63;

    float4 v = ((const float4*)prow)[tid];

    float m = fmaxf(fmaxf(v.x, v.y), fmaxf(v.z, v.w));
#pragma unroll
    for (int off = 32; off > 0; off >>= 1) m = fmaxf(m, __shfl_down(m, off));
    __shared__ float redm[4];
    if (lane == 0) redm[wid] = m;
    __syncthreads();
    const float M = fmaxf(fmaxf(redm[0], redm[1]), fmaxf(redm[2], redm[3]));

    float sh[NH], gh[NH];
#pragma unroll
    for (int h = 0; h < NH; ++h) {
        sh[h] = fminf(fmaxf(strength[n * NH * NH + h * NH + h], 0.01f), 1.0f);
        gh[h] = gate[n * NH + h];
    }

    const float e[4] = { v.x - M, v.y - M, v.z - M, v.w - M };
    float E[4][NH];
    float zsum[NH];
#pragma unroll
    for (int h = 0; h < NH; ++h) zsum[h] = 0.f;
#pragma unroll
    for (int i = 0; i < 4; ++i)
#pragma unroll
        for (int h = 0; h < NH; ++h) {
            const float t = __expf(sh[h] * e[i]);
            E[i][h] = t; zsum[h] += t;
        }

#pragma unroll
    for (int h = 0; h < NH; ++h)
#pragma unroll
        for (int off = 32; off > 0; off >>= 1) zsum[h] += __shfl_down(zsum[h], off);
    __shared__ float redz[4][NH];
    if (lane == 0)
#pragma unroll
        for (int h = 0; h < NH; ++h) redz[wid][h] = zsum[h];
    __syncthreads();

    float wgt[NH];
#pragma unroll
    for (int h = 0; h < NH; ++h) {
        const float Z = redz[0][h] + redz[1][h] + redz[2][h] + redz[3][h];
        wgt[h] = gh[h] / Z;
    }

    bf16x4 o;
#pragma unroll
    for (int i = 0; i < 4; ++i) {
        float s = 0.f;
#pragma unroll
        for (int h = 0; h < NH; ++h) s += wgt[h] * E[i][h];
        o[i] = (bf16)s;
    }
    *(bf16x4*)&Pb[(size_t)row * SEQ + tid * 4] = o;
}

// ---------------------------------------------------------------------------
// PROVEN: HS[z][s][d] = Pb[z] @ Vt[z]^T  (NT, K=SEQ). bf16 out.
// ---------------------------------------------------------------------------
__global__ __launch_bounds__(256) void pv_mfma_kernel(
    const bf16* __restrict__ Pb, const bf16* __restrict__ Vt,
    bf16* __restrict__ HS)
{
    const int z = blockIdx.z;
    const bf16* A = Pb + (size_t)z * SEQ * SEQ;
    const bf16* B = Vt + (size_t)z * HIDDEN * SEQ;
    bf16* C = HS + (size_t)z * SEQ * HIDDEN;

    const int m0 = blockIdx.y * BM, n0 = blockIdx.x * BN;
    floatx4 acc[4][4] = {};
    mfma_nt(A, SEQ, B, SEQ, SEQ, m0, n0, acc);

    const int l = threadIdx.x & 63, w = threadIdx.x >> 6;
    const int rb = m0 + (w >> 1) * 64 + (l >> 4) * 4;
    const int cb = n0 + (w & 1) * 64 + (l & 15);
#pragma unroll
    for (int i = 0; i < 4; ++i)
#pragma unroll
        for (int j = 0; j < 4; ++j)
#pragma unroll
            for (int r = 0; r < 4; ++r)
                C[(size_t)(rb + i * 16 + r) * HIDDEN + cb + j * 16] =
                    (bf16)acc[i][j][r];
}

// ---------------------------------------------------------------------------
// PROVEN: out projection partials, n in blockIdx.z (256 blocks).
// Opart[n][m][o] = HS[n][m] . WoT[n][o]   (fp32)
// ---------------------------------------------------------------------------
__global__ __launch_bounds__(256) void out_partial_kernel(
    const bf16* __restrict__ HS, const bf16* __restrict__ WoT,
    float* __restrict__ Opart)
{
    const int n = blockIdx.z;
    const bf16* A = HS + (size_t)n * (BATCH * SEQ) * HIDDEN;
    const bf16* B = WoT + (size_t)n * HIDDEN * DIM;
    float* C = Opart + (size_t)n * (BATCH * SEQ) * DIM;

    const int m0 = blockIdx.y * BM, n0 = blockIdx.x * BN;
    floatx4 acc[4][4] = {};
    mfma_nt(A, HIDDEN, B, HIDDEN, HIDDEN, m0, n0, acc);

    const int l = threadIdx.x & 63, w = threadIdx.x >> 6;
    const int rb = m0 + (w >> 1) * 64 + (l >> 4) * 4;
    const int cb = n0 + (w & 1) * 64 + (l & 15);
#pragma unroll
    for (int i = 0; i < 4; ++i)
#pragma unroll
        for (int j = 0; j < 4; ++j)
#pragma unroll
            for (int r = 0; r < 4; ++r)
                C[(size_t)(rb + i * 16 + r) * DIM + cb + j * 16] = acc[i][j][r];
}

// ---------------------------------------------------------------------------
// PROVEN: reduce 4 partials + bias + MOD.
// ---------------------------------------------------------------------------
__global__ __launch_bounds__(256) void out_reduce_kernel(
    const float* __restrict__ Opart, const float* __restrict__ bo,
    float* __restrict__ out)
{
    const size_t t = (size_t)blockIdx.x * 256 + threadIdx.x;   // float4 index
    const int c = (int)((t * 4) & (DIM - 1));                  // col of .x
    const size_t stride4 = (size_t)(BATCH * SEQ) * DIM / 4;

    float4 s = ((const float4*)Opart)[t];
#pragma unroll
    for (int n = 1; n < NBLK; ++n) {
        const float4 p = ((const float4*)Opart)[t + n * stride4];
        s.x += p.x; s.y += p.y; s.z += p.z; s.w += p.w;
    }
    float4 bs = make_float4(0.f, 0.f, 0.f, 0.f);
#pragma unroll
    for (int n = 0; n < NBLK; ++n) {
        const float4 b = *(const float4*)(bo + n * DIM + c);
        bs.x += b.x; bs.y += b.y; bs.z += b.z; bs.w += b.w;
    }
    ((float4*)out)[t] = make_float4((s.x + bs.x) * MODF, (s.y + bs.y) * MODF,
                                    (s.z + bs.z) * MODF, (s.w + bs.w) * MODF);
}

// ---------------------------------------------------------------------------
extern "C" void kernel_launch(void* const* d_in, const int* in_sizes, int n_in,
                              void* d_out, int out_size, void* d_ws, size_t ws_size,
                              hipStream_t stream) {
    const float* x        = (const float*)d_in[0];
    const float* Wq       = (const float*)d_in[1];
    const float* bq       = (const float*)d_in[2];
    const float* Wk       = (const float*)d_in[3];
    const float* bk       = (const float*)d_in[4];
    const float* Wv       = (const float*)d_in[5];
    const float* bv       = (const float*)d_in[6];
    const float* Wo       = (const float*)d_in[7];
    const float* bo       = (const float*)d_in[8];
    const float* strength = (const float*)d_in[9];
    const float* gate     = (const float*)d_in[10];
    float* out = (float*)d_out;

    // workspace (MiB offsets), total 66 MiB:
    //   xb  [0,2) | WqT [2,4) | WkT [4,6) | WvT [6,8) | WoT [8,10)
    //   Qh  [10,18) | Kh [18,26) | Vt bf16 [26,34)
    //   Pf fp32 [34,66)
    //   Pb bf16 (16 MiB)   aliases [10,26)  (Qh/Kh dead after scores)
    //   HS bf16 (8 MiB)    aliases [34,42)  (Pf dead after softmax)
    //   Opart fp32 (16 MiB) aliases [42,58) (rest of dead Pf)
    char* ws = (char*)d_ws;
    bf16*  xb    = (bf16*)(ws);
    bf16*  WqT   = (bf16*)(ws + (2u  << 20));
    bf16*  WkT   = (bf16*)(ws + (4u  << 20));
    bf16*  WvT   = (bf16*)(ws + (6u  << 20));
    bf16*  WoT   = (bf16*)(ws + (8u  << 20));
    bf16*  Qh    = (bf16*)(ws + (10u << 20));
    bf16*  Kh    = (bf16*)(ws + (18u << 20));
    bf16*  Vt    = (bf16*)(ws + (26u << 20));
    float* Pf    = (float*)(ws + (34u << 20));
    bf16*  Pb    = (bf16*)(ws + (10u << 20));  // alias over dead Qh/Kh
    bf16*  HS    = (bf16*)(ws + (34u << 20));  // alias over dead Pf (front)
    float* Opart = (float*)(ws + (42u << 20)); // alias over dead Pf (rest)

    // prep
    xconv_kernel<<<dim3((BATCH * SEQ * DIM) / 1024), 256, 0, stream>>>(x, xb);
    transpose_w_kernel<<<dim3(16, 16, 16), 256, 0, stream>>>(
        Wq, Wk, Wv, Wo, WqT, WkT, WvT, WoT);

    // 1) QKV projections via MFMA (V stored transposed): grid (4, 16, 12)
    proj_mfma_kernel<<<dim3(HIDDEN / BN, (BATCH * SEQ) / BM, 3 * NBLK), 256, 0, stream>>>(
        xb, WqT, WkT, WvT, bq, bk, bv, Qh, Kh, Vt);

    // 2) scores via MFMA: grid (8, 8, 8)
    scores_mfma_kernel<<<dim3(SEQ / BN, SEQ / BM, NBLK * BATCH), 256, 0, stream>>>(
        Qh, Kh, Pf);

    // 3) softmax-combine: fp32 in, bf16 out
    softmax_combine_kernel<<<dim3(NBLK * BATCH * SEQ), 256, 0, stream>>>(
        Pf, Pb, strength, gate);

    // 4) head_sum via MFMA: grid (4, 8, 8)
    pv_mfma_kernel<<<dim3(HIDDEN / BN, SEQ / BM, NBLK * BATCH), 256, 0, stream>>>(
        Pb, Vt, HS);

    // 5) out projection partials: grid (4, 16, 4) = 256 blocks
    out_partial_kernel<<<dim3(DIM / BN, (BATCH * SEQ) / BM, NBLK), 256, 0, stream>>>(
        HS, WoT, Opart);

    // 5b) reduce + bias + MOD
    out_reduce_kernel<<<dim3((BATCH * SEQ) * DIM / 4 / 256), 256, 0, stream>>>(
        Opart, bo, out);
}